// Round 12
// baseline (5728.131 us; speedup 1.0000x reference)
//
#include <hip/hip_runtime.h>

#define TSTEPS 50
#define NB (2048 * 256)   // floats per h half-plane (256 rows x 2048 seqs)

__device__ __forceinline__ float sigm(float x) { return 1.0f / (1.0f + expf(-x)); }
__device__ __forceinline__ float gelu_t(float x) {
  float x3 = x * x * x;
  return 0.5f * x * (1.0f + tanhf(0.7978845608028654f * (x + 0.044715f * x3)));
}

// Packed fp32 FMA over the 2 seqs in a float2 lane-pair, with the per-gate
// weight broadcast from the SGPR pair via op_sel (src1 is the one allowed
// SGPR operand). d = a * broadcast(w.lo|w.hi) + c, both halves.
__device__ __forceinline__ float2 pkfma_wlo(float2 a, float2 w, float2 c) {
  float2 d;
  asm("v_pk_fma_f32 %0, %1, %2, %3 op_sel_hi:[1,0,1]"
      : "=v"(d) : "v"(a), "s"(w), "v"(c));
  return d;
}
__device__ __forceinline__ float2 pkfma_whi(float2 a, float2 w, float2 c) {
  float2 d;
  asm("v_pk_fma_f32 %0, %1, %2, %3 op_sel:[0,1,0] op_sel_hi:[1,1,1]"
      : "=v"(d) : "v"(a), "s"(w), "v"(c));
  return d;
}

// m-group barrier (16 blocks). Plain __threadfence pair only (R4-proven; R6's
// buffer_inv was a 4.4GB disaster). No runtime-indexed local arrays (R9: 34GB).
__device__ __forceinline__ void mg_barrier(unsigned* bar, unsigned target) {
  __syncthreads();
  if (threadIdx.x == 0) {
    __threadfence();
    atomicAdd(bar, 1u);
    while (atomicAdd(bar, 0u) < target) __builtin_amdgcn_s_sleep(4);
    __threadfence();
  }
  __syncthreads();
}

// Pack W per-jcol streams: Wp1[jcol][k=0..271][4 gates], Wp2[jcol][k=0..511][4].
__global__ void __launch_bounds__(256)
pack_w(const float* __restrict__ Wx1, const float* __restrict__ Wh1,
       const float* __restrict__ Wx2, const float* __restrict__ Wh2,
       float* __restrict__ Wp1, float* __restrict__ Wp2, unsigned* __restrict__ bar) {
  const int idx = blockIdx.x * 256 + threadIdx.x;
  if (blockIdx.x == 0 && threadIdx.x < 256) bar[threadIdx.x] = 0u;
  if (idx < 256 * 272 * 4) {
    int g = idx & 3, k = (idx >> 2) % 272, jcol = idx / (272 * 4);
    int col = (g << 8) + jcol;
    Wp1[idx] = (k < 16) ? Wx1[(k << 10) + col] : Wh1[((k - 16) << 10) + col];
  }
  if (idx < 256 * 512 * 4) {
    int g = idx & 3, k = (idx >> 2) & 511, jcol = idx >> 11;
    int col = (g << 8) + jcol;
    Wp2[idx] = (k < 256) ? Wx2[(k << 10) + col] : Wh2[((k - 256) << 10) + col];
  }
}

// x[seq][t*16+d] -> xT[t*16+d][seq]
__global__ void __launch_bounds__(256)
transpose_x(const float* __restrict__ x, float* __restrict__ xT) {
  __shared__ float Ts[64][65];
  const int st = blockIdx.x & 31;
  const int tt = blockIdx.x >> 5;
  const int s0 = st << 6, t0 = tt << 6;
  const int r = threadIdx.x >> 6;
  const int c = threadIdx.x & 63;
  #pragma unroll
  for (int i = 0; i < 16; ++i) {
    int row = r + (i << 2);
    int td = t0 + c;
    if (td < 800) Ts[row][c] = x[(s0 + row) * 800 + td];
  }
  __syncthreads();
  #pragma unroll
  for (int i = 0; i < 16; ++i) {
    int row = r + (i << 2);
    int td = t0 + row;
    if (td < 800) xT[td * 2048 + s0 + c] = Ts[c][row];
  }
}

// Persistent fused 2-layer LSTM + time-mean pool. Structure = verified R11
// (16mg x 16jg, 1024thr/16 waves, wave-per-jcol uniform W, 128-row LDS chunks,
// arithmetic chunk plan), inner loop re-expressed as v_pk_fma_f32 over the
// (seq0,seq1) pair: 4 pk_fma replace 8 v_fma per k per z-target.
__global__ void __launch_bounds__(1024, 1)
lstm_fused(const float* __restrict__ xT,
           const float* __restrict__ Wp1, const float* __restrict__ Wp2,
           const float* __restrict__ b1, const float* __restrict__ b2,
           float* __restrict__ pair0, float* __restrict__ pair1,
           float* __restrict__ xg, unsigned* __restrict__ bar)
{
  __shared__ float As0[128 * 128];         // 64KB
  __shared__ float As1[128 * 128];         // 64KB
  __shared__ float Asx[16 * 128];          // 8KB x chunk

  const int tid = threadIdx.x;
  const int lane = tid & 63;
  const int wv = __builtin_amdgcn_readfirstlane(tid >> 6);   // 0..15, uniform
  const int blk = blockIdx.x;
  const int mg = blk & 15, jg = blk >> 4;
  const int mgoff = mg << 7;               // 128 seqs
  const int jcol = (jg << 4) + wv;         // 0..255, wave-uniform
  unsigned* mybar = bar + (mg << 4);

  const float* wp1 = Wp1 + (size_t)jcol * (272 * 4);
  const float* wp2 = Wp2 + (size_t)jcol * (512 * 4);

  float4 zb1, zb2;
  #pragma unroll
  for (int g = 0; g < 4; ++g) {
    (&zb1.x)[g] = b1[(g << 8) + jcol];
    (&zb2.x)[g] = b2[(g << 8) + jcol];
  }

  float c1[2] = {0, 0}, c2[2] = {0, 0}, pool[2] = {0, 0};
  // z1s[g] / z2s[g]: float2 packing (seq0, seq1) for gate g (g-loop unrolled).
  float2 z1s[4], z2s[4];

  const int srow = tid >> 5;               // 0..31
  const int scol = (tid & 31) << 2;        // 0..124 (floats)

  const int aoff = lane << 1;
  auto consume_x = [&]() {                           // 16 k-rows -> z1 (W1x)
    float2 Aq[8];
    #pragma unroll
    for (int i = 0; i < 8; ++i) Aq[i] = *(const float2*)(Asx + (i << 7) + aoff);
    #pragma unroll
    for (int k = 0; k < 16; ++k) {
      float2 a = Aq[k & 7];
      float2 w01 = *(const float2*)(wp1 + (k << 2));
      float2 w23 = *(const float2*)(wp1 + (k << 2) + 2);
      z1s[0] = pkfma_wlo(a, w01, z1s[0]);
      z1s[1] = pkfma_whi(a, w01, z1s[1]);
      z1s[2] = pkfma_wlo(a, w23, z1s[2]);
      z1s[3] = pkfma_whi(a, w23, z1s[3]);
      int kn = k + 8; kn = kn > 15 ? 15 : kn;
      Aq[k & 7] = *(const float2*)(Asx + (kn << 7) + aoff);
    }
  };
  auto consume_dual = [&](const float* buf, int kk0) {  // 128 h1 rows -> z1,z2
    const float* w1b = wp1 + ((16 + kk0) << 2);
    const float* w2b = wp2 + (kk0 << 2);
    float2 Aq[8];
    #pragma unroll
    for (int i = 0; i < 8; ++i) Aq[i] = *(const float2*)(buf + (i << 7) + aoff);
    #pragma unroll 8
    for (int k = 0; k < 128; ++k) {
      float2 a = Aq[k & 7];
      float2 u01 = *(const float2*)(w1b + (k << 2));
      float2 u23 = *(const float2*)(w1b + (k << 2) + 2);
      float2 v01 = *(const float2*)(w2b + (k << 2));
      float2 v23 = *(const float2*)(w2b + (k << 2) + 2);
      z1s[0] = pkfma_wlo(a, u01, z1s[0]);
      z1s[1] = pkfma_whi(a, u01, z1s[1]);
      z1s[2] = pkfma_wlo(a, u23, z1s[2]);
      z1s[3] = pkfma_whi(a, u23, z1s[3]);
      z2s[0] = pkfma_wlo(a, v01, z2s[0]);
      z2s[1] = pkfma_whi(a, v01, z2s[1]);
      z2s[2] = pkfma_wlo(a, v23, z2s[2]);
      z2s[3] = pkfma_whi(a, v23, z2s[3]);
      int kn = k + 8; kn = kn > 127 ? 127 : kn;
      Aq[k & 7] = *(const float2*)(buf + (kn << 7) + aoff);
    }
  };
  auto consume_w2 = [&](const float* buf, int koff) {   // 128 rows -> z2 only
    const float* w2b = wp2 + (koff << 2);
    float2 Aq[8];
    #pragma unroll
    for (int i = 0; i < 8; ++i) Aq[i] = *(const float2*)(buf + (i << 7) + aoff);
    #pragma unroll 8
    for (int k = 0; k < 128; ++k) {
      float2 a = Aq[k & 7];
      float2 v01 = *(const float2*)(w2b + (k << 2));
      float2 v23 = *(const float2*)(w2b + (k << 2) + 2);
      z2s[0] = pkfma_wlo(a, v01, z2s[0]);
      z2s[1] = pkfma_whi(a, v01, z2s[1]);
      z2s[2] = pkfma_wlo(a, v23, z2s[2]);
      z2s[3] = pkfma_whi(a, v23, z2s[3]);
      int kn = k + 8; kn = kn > 127 ? 127 : kn;
      Aq[k & 7] = *(const float2*)(buf + (kn << 7) + aoff);
    }
  };

  for (int p = 0; p <= TSTEPS; ++p) {
    float* const pw = (p & 1) ? pair1 : pair0;
    const float* const prd = (p & 1) ? pair0 : pair1;
    const bool doL1 = (p < TSTEPS);
    const bool doL2 = (p >= 1);
    const bool doH2 = (p >= 2);
    const int nch = (doL2 ? 2 : 0) + (doH2 ? 2 : 0);   // 128-row h chunks
    const float* const xsrc = xT + (size_t)(p << 4) * 2048 + mgoff;

    if (doL1) {
      z1s[0] = make_float2(zb1.x, zb1.x);
      z1s[1] = make_float2(zb1.y, zb1.y);
      z1s[2] = make_float2(zb1.z, zb1.z);
      z1s[3] = make_float2(zb1.w, zb1.w);
    }
    if (doL2) {
      z2s[0] = make_float2(zb2.x, zb2.x);
      z2s[1] = make_float2(zb2.y, zb2.y);
      z2s[2] = make_float2(zb2.z, zb2.z);
      z2s[3] = make_float2(zb2.w, zb2.w);
    }

    // ---- stage x chunk (16 rows) and h chunk 0 (128 rows) together ----
    float4 Sx, S0, S1, S2, S3;
    if (doL1 && srow < 16) Sx = *(const float4*)(xsrc + (size_t)srow * 2048 + scol);
    if (doL2) {
      const float* b0 = prd + mgoff;       // chunk 0 = rows 0..127
      S0 = *(const float4*)(b0 + (size_t)(srow)        * 2048 + scol);
      S1 = *(const float4*)(b0 + (size_t)(srow + 32)   * 2048 + scol);
      S2 = *(const float4*)(b0 + (size_t)(srow + 64)   * 2048 + scol);
      S3 = *(const float4*)(b0 + (size_t)(srow + 96)   * 2048 + scol);
    }
    if (doL1 && srow < 16) *(float4*)(Asx + (srow << 7) + scol) = Sx;
    if (doL2) {
      *(float4*)(As0 + ((srow)       << 7) + scol) = S0;
      *(float4*)(As0 + ((srow + 32)  << 7) + scol) = S1;
      *(float4*)(As0 + ((srow + 64)  << 7) + scol) = S2;
      *(float4*)(As0 + ((srow + 96)  << 7) + scol) = S3;
    }
    __syncthreads();

    if (!doL2) {                           // p==0: only the x chunk
      consume_x();
    } else {
      int cur = 0;
      for (int c = 0; c < nch; ++c) {
        if (c + 1 < nch) {                 // T14: issue next chunk loads early
          const float* bn = prd + ((size_t)(c + 1) << 7) * 2048 + mgoff;
          S0 = *(const float4*)(bn + (size_t)(srow)      * 2048 + scol);
          S1 = *(const float4*)(bn + (size_t)(srow + 32) * 2048 + scol);
          S2 = *(const float4*)(bn + (size_t)(srow + 64) * 2048 + scol);
          S3 = *(const float4*)(bn + (size_t)(srow + 96) * 2048 + scol);
        }
        const float* buf = cur ? As1 : As0;
        if (doL1 && c == 0) consume_x();
        if (doL1 && c < 2)  consume_dual(buf, c << 7);
        else                consume_w2(buf, c << 7);
        if (c + 1 < nch) {
          float* nbuf = cur ? As0 : As1;
          *(float4*)(nbuf + ((srow)       << 7) + scol) = S0;
          *(float4*)(nbuf + ((srow + 32)  << 7) + scol) = S1;
          *(float4*)(nbuf + ((srow + 64)  << 7) + scol) = S2;
          *(float4*)(nbuf + ((srow + 96)  << 7) + scol) = S3;
          cur ^= 1;
        }
        __syncthreads();
      }
    }

    // epilogues (z1s[g] = (seq0,seq1) of gate g; gates i,f,g,o = 0..3)
    if (doL1) {
      float2 hv;
      #pragma unroll
      for (int m = 0; m < 2; ++m) {
        float zi = m ? z1s[0].y : z1s[0].x;
        float zf = m ? z1s[1].y : z1s[1].x;
        float zg = m ? z1s[2].y : z1s[2].x;
        float zo = m ? z1s[3].y : z1s[3].x;
        float iv = sigm(zi), fv = sigm(zf);
        float gv = tanhf(zg), ov = sigm(zo);
        c1[m] = fv * c1[m] + iv * gv;
        (&hv.x)[m] = ov * tanhf(c1[m]);
      }
      *(float2*)(pw + (size_t)jcol * 2048 + mgoff + (lane << 1)) = hv;
    }
    if (doL2) {
      float2 hv;
      #pragma unroll
      for (int m = 0; m < 2; ++m) {
        float zi = m ? z2s[0].y : z2s[0].x;
        float zf = m ? z2s[1].y : z2s[1].x;
        float zg = m ? z2s[2].y : z2s[2].x;
        float zo = m ? z2s[3].y : z2s[3].x;
        float iv = sigm(zi), fv = sigm(zf);
        float gv = tanhf(zg), ov = sigm(zo);
        c2[m] = fv * c2[m] + iv * gv;
        float h = ov * tanhf(c2[m]);
        pool[m] += h;
        (&hv.x)[m] = h;
      }
      *(float2*)(pw + (size_t)(256 + jcol) * 2048 + mgoff + (lane << 1)) = hv;
    }

    if (p < TSTEPS) mg_barrier(mybar, (unsigned)(p + 1) * 16u);
  }

  #pragma unroll
  for (int m = 0; m < 2; ++m)
    xg[(size_t)(mgoff + (lane << 1) + m) * 256 + jcol] = pool[m] * (1.0f / 50.0f);
}

// ---- GAT (verified R1-R11) --------------------------------------------------
__global__ void __launch_bounds__(256)
gat_feat(const float* __restrict__ xin, const float* __restrict__ gW,
         const float* __restrict__ a_src, const float* __restrict__ a_dst,
         float* __restrict__ hfeat, float* __restrict__ es, float* __restrict__ ed)
{
  __shared__ float Xs[8][260];
  const int tid = threadIdx.x;
  const int r0 = blockIdx.x << 3;
  #pragma unroll
  for (int i = 0; i < 8; ++i) Xs[i][tid] = xin[((r0 + i) << 8) + tid];
  __syncthreads();
  float acc[8];
  #pragma unroll
  for (int i = 0; i < 8; ++i) acc[i] = 0.0f;
  for (int k = 0; k < 256; k += 4) {
    const float w0 = gW[(k + 0) * 256 + tid];
    const float w1 = gW[(k + 1) * 256 + tid];
    const float w2 = gW[(k + 2) * 256 + tid];
    const float w3 = gW[(k + 3) * 256 + tid];
    #pragma unroll
    for (int i = 0; i < 8; ++i)
      acc[i] += Xs[i][k] * w0 + Xs[i][k + 1] * w1 + Xs[i][k + 2] * w2 + Xs[i][k + 3] * w3;
  }
  const int h = tid >> 6;
  const int lane = tid & 63;
  const float asv = a_src[(h << 6) + lane];
  const float adv = a_dst[(h << 6) + lane];
  #pragma unroll
  for (int i = 0; i < 8; ++i) {
    hfeat[((r0 + i) << 8) + tid] = acc[i];
    float pse = acc[i] * asv;
    float pde = acc[i] * adv;
    #pragma unroll
    for (int off = 32; off > 0; off >>= 1) {
      pse += __shfl_down(pse, off);
      pde += __shfl_down(pde, off);
    }
    if (lane == 0) {
      es[((r0 + i) << 2) + h] = pse;
      ed[((r0 + i) << 2) + h] = pde;
    }
  }
}

__global__ void __launch_bounds__(256)
gat_out(const float* __restrict__ hfeat, const float* __restrict__ es, const float* __restrict__ ed,
        const float* __restrict__ gb, float* __restrict__ yout)
{
  __shared__ float exs[32][4];
  __shared__ float invden[4];
  const int tid = threadIdx.x;
  const int rbase = blockIdx.x << 5;
  if (tid < 128) {
    const int u = tid >> 2, h = tid & 3;
    float l = es[((rbase + u) << 2) + h] + ed[(rbase << 2) + h];
    exs[u][h] = (l < 0.0f) ? 0.2f * l : l;
  }
  __syncthreads();
  if (tid < 4) {
    const int h = tid;
    float m = -1e30f;
    for (int u = 0; u < 32; ++u) m = fmaxf(m, exs[u][h]);
    float s = 0.0f;
    for (int u = 0; u < 32; ++u) { float e = expf(exs[u][h] - m); exs[u][h] = e; s += e; }
    s += exs[0][h];                        // duplicate 0->0 edge
    invden[h] = 1.0f / (s + 1e-9f);
  }
  __syncthreads();
  const int h = tid >> 6;
  const float h0 = hfeat[(rbase << 8) + tid];
  float s = exs[0][h] * h0;
  for (int u = 0; u < 32; ++u)
    s += exs[u][h] * hfeat[((rbase + u) << 8) + tid];
  const float bias = gb[tid];
  const float inv1 = 1.0f / (1.0f + 1e-9f);
  yout[(rbase << 8) + tid] = gelu_t(s * invden[h] + bias);
  const float gv = gelu_t(h0 * inv1 + bias);
  for (int v = 1; v < 32; ++v)
    yout[((rbase + v) << 8) + tid] = gv;
}

// ---- launch -----------------------------------------------------------------
extern "C" void kernel_launch(void* const* d_in, const int* in_sizes, int n_in,
                              void* d_out, int out_size, void* d_ws, size_t ws_size,
                              hipStream_t stream) {
  (void)in_sizes; (void)n_in; (void)out_size; (void)ws_size;
  const float* states = (const float*)d_in[0];
  const float* Wx1 = (const float*)d_in[1];
  const float* Wh1 = (const float*)d_in[2];
  const float* b1  = (const float*)d_in[3];
  const float* Wx2 = (const float*)d_in[4];
  const float* Wh2 = (const float*)d_in[5];
  const float* b2  = (const float*)d_in[6];
  const float* gW1 = (const float*)d_in[7];
  const float* gas1 = (const float*)d_in[8];
  const float* gad1 = (const float*)d_in[9];
  const float* gb1 = (const float*)d_in[10];
  const float* gW2 = (const float*)d_in[11];
  const float* gas2 = (const float*)d_in[12];
  const float* gad2 = (const float*)d_in[13];
  const float* gb2 = (const float*)d_in[14];

  float* ws = (float*)d_ws;
  float* pair0 = ws;                       // 2*NB floats (h1|h2 plane)
  float* pair1 = ws + 2 * (size_t)NB;      // 2*NB floats
  float* xg    = ws + 4 * (size_t)NB;      // NB floats
  float* xT    = ws + 5 * (size_t)NB;      // 800*2048 floats
  float* Wp1   = xT + 800 * 2048;          // 256*272*4 = 278528
  float* Wp2   = Wp1 + 278528;             // 256*512*4 = 524288
  unsigned* bar = (unsigned*)(Wp2 + 524288);
  // GAT aliases (pair buffers dead after lstm)
  float* y1    = pair0;
  float* hfeat = pair0 + NB;
  float* es    = pair1;
  float* ed    = pair1 + 2048 * 4;
  float* dout  = (float*)d_out;

  pack_w<<<dim3(2048), dim3(256), 0, stream>>>(Wx1, Wh1, Wx2, Wh2, Wp1, Wp2, bar);
  transpose_x<<<dim3(32 * 13), dim3(256), 0, stream>>>(states, xT);

  void* args[] = { (void*)&xT, (void*)&Wp1, (void*)&Wp2, (void*)&b1, (void*)&b2,
                   (void*)&pair0, (void*)&pair1, (void*)&xg, (void*)&bar };
  hipError_t err = hipLaunchCooperativeKernel((void*)lstm_fused, dim3(256), dim3(1024),
                                              args, 0, stream);
  if (err != hipSuccess) {
    // Fallback: grid == 1 block/CU capacity, co-resident anyway. NEVER drop
    // the launch silently (R8: zero-output failure).
    lstm_fused<<<dim3(256), dim3(1024), 0, stream>>>(xT, Wp1, Wp2, b1, b2,
                                                     pair0, pair1, xg, bar);
  }

  gat_feat<<<dim3(256), dim3(256), 0, stream>>>(xg, gW1, gas1, gad1, hfeat, es, ed);
  gat_out<<<dim3(64), dim3(256), 0, stream>>>(hfeat, es, ed, gb1, y1);
  gat_feat<<<dim3(256), dim3(256), 0, stream>>>(y1, gW2, gas2, gad2, hfeat, es, ed);
  gat_out<<<dim3(64), dim3(256), 0, stream>>>(hfeat, es, ed, gb2, dout);
}

// Round 13
// 3902.442 us; speedup vs baseline: 1.4678x; 1.4678x over previous
//
#include <hip/hip_runtime.h>

#define TSTEPS 50
#define NB (2048 * 256)   // floats per h half-plane (256 rows x 2048 seqs)

__device__ __forceinline__ float sigm(float x) { return 1.0f / (1.0f + expf(-x)); }
__device__ __forceinline__ float gelu_t(float x) {
  float x3 = x * x * x;
  return 0.5f * x * (1.0f + tanhf(0.7978845608028654f * (x + 0.044715f * x3)));
}

// za[m][g] += a[m] * w[g]. Inline fn, not macro (macro param/member collisions R5,R7).
// Plain v_fma only: inline-asm pk_fma with "s" operands forced s_load W streams,
// whose in-order lgkmcnt waits drained the ds_read pipeline (R12: 2x regression).
__device__ __forceinline__ void fma8(float (&za)[2][4], const float2 a, const float4 w) {
  za[0][0] += a.x * w.x; za[0][1] += a.x * w.y; za[0][2] += a.x * w.z; za[0][3] += a.x * w.w;
  za[1][0] += a.y * w.x; za[1][1] += a.y * w.y; za[1][2] += a.y * w.z; za[1][3] += a.y * w.w;
}

// m-group barrier (16 blocks). Plain __threadfence pair only (R4-proven; R6's
// buffer_inv was a 4.4GB disaster). No runtime-indexed local arrays (R9: 34GB).
__device__ __forceinline__ void mg_barrier(unsigned* bar, unsigned target) {
  __syncthreads();
  if (threadIdx.x == 0) {
    __threadfence();
    atomicAdd(bar, 1u);
    while (atomicAdd(bar, 0u) < target) __builtin_amdgcn_s_sleep(4);
    __threadfence();
  }
  __syncthreads();
}

// Pack W per-jcol streams: Wp1[jcol][k=0..271][4 gates], Wp2[jcol][k=0..511][4].
__global__ void __launch_bounds__(256)
pack_w(const float* __restrict__ Wx1, const float* __restrict__ Wh1,
       const float* __restrict__ Wx2, const float* __restrict__ Wh2,
       float* __restrict__ Wp1, float* __restrict__ Wp2, unsigned* __restrict__ bar) {
  const int idx = blockIdx.x * 256 + threadIdx.x;
  if (blockIdx.x == 0 && threadIdx.x < 256) bar[threadIdx.x] = 0u;
  if (idx < 256 * 272 * 4) {
    int g = idx & 3, k = (idx >> 2) % 272, jcol = idx / (272 * 4);
    int col = (g << 8) + jcol;
    Wp1[idx] = (k < 16) ? Wx1[(k << 10) + col] : Wh1[((k - 16) << 10) + col];
  }
  if (idx < 256 * 512 * 4) {
    int g = idx & 3, k = (idx >> 2) & 511, jcol = idx >> 11;
    int col = (g << 8) + jcol;
    Wp2[idx] = (k < 256) ? Wx2[(k << 10) + col] : Wh2[((k - 256) << 10) + col];
  }
}

// x[seq][t*16+d] -> xT[t*16+d][seq]
__global__ void __launch_bounds__(256)
transpose_x(const float* __restrict__ x, float* __restrict__ xT) {
  __shared__ float Ts[64][65];
  const int st = blockIdx.x & 31;
  const int tt = blockIdx.x >> 5;
  const int s0 = st << 6, t0 = tt << 6;
  const int r = threadIdx.x >> 6;
  const int c = threadIdx.x & 63;
  #pragma unroll
  for (int i = 0; i < 16; ++i) {
    int row = r + (i << 2);
    int td = t0 + c;
    if (td < 800) Ts[row][c] = x[(s0 + row) * 800 + td];
  }
  __syncthreads();
  #pragma unroll
  for (int i = 0; i < 16; ++i) {
    int row = r + (i << 2);
    int td = t0 + row;
    if (td < 800) xT[td * 2048 + s0 + c] = Ts[c][row];
  }
}

// Persistent fused 2-layer LSTM + time-mean pool. Structure = verified R11
// (16mg x 16jg, 1024thr/16 waves, wave-per-jcol uniform W, 128-row LDS chunks,
// arithmetic chunk plan) + R13's depth-4 W register carousel: W loads issue
// 4 k-steps before use so the ~200cyc L2 hit latency hides under FMA issue.
__global__ void __launch_bounds__(1024, 1)
lstm_fused(const float* __restrict__ xT,
           const float* __restrict__ Wp1, const float* __restrict__ Wp2,
           const float* __restrict__ b1, const float* __restrict__ b2,
           float* __restrict__ pair0, float* __restrict__ pair1,
           float* __restrict__ xg, unsigned* __restrict__ bar)
{
  __shared__ float As0[128 * 128];         // 64KB
  __shared__ float As1[128 * 128];         // 64KB
  __shared__ float Asx[16 * 128];          // 8KB x chunk

  const int tid = threadIdx.x;
  const int lane = tid & 63;
  const int wv = __builtin_amdgcn_readfirstlane(tid >> 6);   // 0..15, uniform
  const int blk = blockIdx.x;
  const int mg = blk & 15, jg = blk >> 4;
  const int mgoff = mg << 7;               // 128 seqs
  const int jcol = (jg << 4) + wv;         // 0..255, wave-uniform
  unsigned* mybar = bar + (mg << 4);

  const float* wp1 = Wp1 + (size_t)jcol * (272 * 4);
  const float* wp2 = Wp2 + (size_t)jcol * (512 * 4);

  float4 zb1, zb2;
  #pragma unroll
  for (int g = 0; g < 4; ++g) {
    (&zb1.x)[g] = b1[(g << 8) + jcol];
    (&zb2.x)[g] = b2[(g << 8) + jcol];
  }

  float c1[2] = {0, 0}, c2[2] = {0, 0}, pool[2] = {0, 0};
  float z1[2][4], z2[2][4];

  const int srow = tid >> 5;               // 0..31
  const int scol = (tid & 31) << 2;        // 0..124 (floats)

  const int aoff = lane << 1;
  auto consume_x = [&]() {                           // 16 k-rows -> z1 (W1x)
    float2 Aq[4];
    float4 Wq[4];
    #pragma unroll
    for (int i = 0; i < 4; ++i) {
      Aq[i] = *(const float2*)(Asx + (i << 7) + aoff);
      Wq[i] = *(const float4*)(wp1 + (i << 2));
    }
    #pragma unroll
    for (int k = 0; k < 16; ++k) {
      float2 a = Aq[k & 3];
      float4 w = Wq[k & 3];
      fma8(z1, a, w);
      int kn = k + 4; kn = kn > 15 ? 15 : kn;
      Aq[k & 3] = *(const float2*)(Asx + (kn << 7) + aoff);
      Wq[k & 3] = *(const float4*)(wp1 + (kn << 2));
    }
  };
  auto consume_dual = [&](const float* buf, int kk0) {  // 128 h1 rows -> z1,z2
    const float* w1b = wp1 + ((16 + kk0) << 2);
    const float* w2b = wp2 + (kk0 << 2);
    float2 Aq[8];
    float4 Wu[4], Wv[4];
    #pragma unroll
    for (int i = 0; i < 8; ++i) Aq[i] = *(const float2*)(buf + (i << 7) + aoff);
    #pragma unroll
    for (int i = 0; i < 4; ++i) {
      Wu[i] = *(const float4*)(w1b + (i << 2));
      Wv[i] = *(const float4*)(w2b + (i << 2));
    }
    #pragma unroll 8
    for (int k = 0; k < 128; ++k) {
      float2 a = Aq[k & 7];
      float4 wu = Wu[k & 3];
      float4 wvv = Wv[k & 3];
      fma8(z1, a, wu);
      fma8(z2, a, wvv);
      int kn8 = k + 8; kn8 = kn8 > 127 ? 127 : kn8;
      int kn4 = k + 4; kn4 = kn4 > 127 ? 127 : kn4;
      Aq[k & 7] = *(const float2*)(buf + (kn8 << 7) + aoff);
      Wu[k & 3] = *(const float4*)(w1b + (kn4 << 2));
      Wv[k & 3] = *(const float4*)(w2b + (kn4 << 2));
    }
  };
  auto consume_w2 = [&](const float* buf, int koff) {   // 128 rows -> z2 only
    const float* w2b = wp2 + (koff << 2);
    float2 Aq[8];
    float4 Wq[4];
    #pragma unroll
    for (int i = 0; i < 8; ++i) Aq[i] = *(const float2*)(buf + (i << 7) + aoff);
    #pragma unroll
    for (int i = 0; i < 4; ++i) Wq[i] = *(const float4*)(w2b + (i << 2));
    #pragma unroll 8
    for (int k = 0; k < 128; ++k) {
      float2 a = Aq[k & 7];
      float4 w = Wq[k & 3];
      fma8(z2, a, w);
      int kn8 = k + 8; kn8 = kn8 > 127 ? 127 : kn8;
      int kn4 = k + 4; kn4 = kn4 > 127 ? 127 : kn4;
      Aq[k & 7] = *(const float2*)(buf + (kn8 << 7) + aoff);
      Wq[k & 3] = *(const float4*)(w2b + (kn4 << 2));
    }
  };

  for (int p = 0; p <= TSTEPS; ++p) {
    float* const pw = (p & 1) ? pair1 : pair0;
    const float* const prd = (p & 1) ? pair0 : pair1;
    const bool doL1 = (p < TSTEPS);
    const bool doL2 = (p >= 1);
    const bool doH2 = (p >= 2);
    const int nch = (doL2 ? 2 : 0) + (doH2 ? 2 : 0);   // 128-row h chunks
    const float* const xsrc = xT + (size_t)(p << 4) * 2048 + mgoff;

    if (doL1) {
      #pragma unroll
      for (int m = 0; m < 2; ++m) {
        z1[m][0] = zb1.x; z1[m][1] = zb1.y; z1[m][2] = zb1.z; z1[m][3] = zb1.w;
      }
    }
    if (doL2) {
      #pragma unroll
      for (int m = 0; m < 2; ++m) {
        z2[m][0] = zb2.x; z2[m][1] = zb2.y; z2[m][2] = zb2.z; z2[m][3] = zb2.w;
      }
    }

    // ---- stage x chunk (16 rows) and h chunk 0 (128 rows) together ----
    float4 Sx, S0, S1, S2, S3;
    if (doL1 && srow < 16) Sx = *(const float4*)(xsrc + (size_t)srow * 2048 + scol);
    if (doL2) {
      const float* b0 = prd + mgoff;       // chunk 0 = rows 0..127
      S0 = *(const float4*)(b0 + (size_t)(srow)        * 2048 + scol);
      S1 = *(const float4*)(b0 + (size_t)(srow + 32)   * 2048 + scol);
      S2 = *(const float4*)(b0 + (size_t)(srow + 64)   * 2048 + scol);
      S3 = *(const float4*)(b0 + (size_t)(srow + 96)   * 2048 + scol);
    }
    if (doL1 && srow < 16) *(float4*)(Asx + (srow << 7) + scol) = Sx;
    if (doL2) {
      *(float4*)(As0 + ((srow)       << 7) + scol) = S0;
      *(float4*)(As0 + ((srow + 32)  << 7) + scol) = S1;
      *(float4*)(As0 + ((srow + 64)  << 7) + scol) = S2;
      *(float4*)(As0 + ((srow + 96)  << 7) + scol) = S3;
    }
    __syncthreads();

    if (!doL2) {                           // p==0: only the x chunk
      consume_x();
    } else {
      int cur = 0;
      for (int c = 0; c < nch; ++c) {
        if (c + 1 < nch) {                 // T14: issue next chunk loads early
          const float* bn = prd + ((size_t)(c + 1) << 7) * 2048 + mgoff;
          S0 = *(const float4*)(bn + (size_t)(srow)      * 2048 + scol);
          S1 = *(const float4*)(bn + (size_t)(srow + 32) * 2048 + scol);
          S2 = *(const float4*)(bn + (size_t)(srow + 64) * 2048 + scol);
          S3 = *(const float4*)(bn + (size_t)(srow + 96) * 2048 + scol);
        }
        const float* buf = cur ? As1 : As0;
        if (doL1 && c == 0) consume_x();
        if (doL1 && c < 2)  consume_dual(buf, c << 7);
        else                consume_w2(buf, c << 7);
        if (c + 1 < nch) {
          float* nbuf = cur ? As0 : As1;
          *(float4*)(nbuf + ((srow)       << 7) + scol) = S0;
          *(float4*)(nbuf + ((srow + 32)  << 7) + scol) = S1;
          *(float4*)(nbuf + ((srow + 64)  << 7) + scol) = S2;
          *(float4*)(nbuf + ((srow + 96)  << 7) + scol) = S3;
          cur ^= 1;
        }
        __syncthreads();
      }
    }

    // epilogues
    if (doL1) {
      float2 hv;
      #pragma unroll
      for (int m = 0; m < 2; ++m) {
        float iv = sigm(z1[m][0]), fv = sigm(z1[m][1]);
        float gv = tanhf(z1[m][2]), ov = sigm(z1[m][3]);
        c1[m] = fv * c1[m] + iv * gv;
        (&hv.x)[m] = ov * tanhf(c1[m]);
      }
      *(float2*)(pw + (size_t)jcol * 2048 + mgoff + (lane << 1)) = hv;
    }
    if (doL2) {
      float2 hv;
      #pragma unroll
      for (int m = 0; m < 2; ++m) {
        float iv = sigm(z2[m][0]), fv = sigm(z2[m][1]);
        float gv = tanhf(z2[m][2]), ov = sigm(z2[m][3]);
        c2[m] = fv * c2[m] + iv * gv;
        float h = ov * tanhf(c2[m]);
        pool[m] += h;
        (&hv.x)[m] = h;
      }
      *(float2*)(pw + (size_t)(256 + jcol) * 2048 + mgoff + (lane << 1)) = hv;
    }

    if (p < TSTEPS) mg_barrier(mybar, (unsigned)(p + 1) * 16u);
  }

  #pragma unroll
  for (int m = 0; m < 2; ++m)
    xg[(size_t)(mgoff + (lane << 1) + m) * 256 + jcol] = pool[m] * (1.0f / 50.0f);
}

// ---- GAT (verified R1-R12) --------------------------------------------------
__global__ void __launch_bounds__(256)
gat_feat(const float* __restrict__ xin, const float* __restrict__ gW,
         const float* __restrict__ a_src, const float* __restrict__ a_dst,
         float* __restrict__ hfeat, float* __restrict__ es, float* __restrict__ ed)
{
  __shared__ float Xs[8][260];
  const int tid = threadIdx.x;
  const int r0 = blockIdx.x << 3;
  #pragma unroll
  for (int i = 0; i < 8; ++i) Xs[i][tid] = xin[((r0 + i) << 8) + tid];
  __syncthreads();
  float acc[8];
  #pragma unroll
  for (int i = 0; i < 8; ++i) acc[i] = 0.0f;
  for (int k = 0; k < 256; k += 4) {
    const float w0 = gW[(k + 0) * 256 + tid];
    const float w1 = gW[(k + 1) * 256 + tid];
    const float w2 = gW[(k + 2) * 256 + tid];
    const float w3 = gW[(k + 3) * 256 + tid];
    #pragma unroll
    for (int i = 0; i < 8; ++i)
      acc[i] += Xs[i][k] * w0 + Xs[i][k + 1] * w1 + Xs[i][k + 2] * w2 + Xs[i][k + 3] * w3;
  }
  const int h = tid >> 6;
  const int lane = tid & 63;
  const float asv = a_src[(h << 6) + lane];
  const float adv = a_dst[(h << 6) + lane];
  #pragma unroll
  for (int i = 0; i < 8; ++i) {
    hfeat[((r0 + i) << 8) + tid] = acc[i];
    float pse = acc[i] * asv;
    float pde = acc[i] * adv;
    #pragma unroll
    for (int off = 32; off > 0; off >>= 1) {
      pse += __shfl_down(pse, off);
      pde += __shfl_down(pde, off);
    }
    if (lane == 0) {
      es[((r0 + i) << 2) + h] = pse;
      ed[((r0 + i) << 2) + h] = pde;
    }
  }
}

__global__ void __launch_bounds__(256)
gat_out(const float* __restrict__ hfeat, const float* __restrict__ es, const float* __restrict__ ed,
        const float* __restrict__ gb, float* __restrict__ yout)
{
  __shared__ float exs[32][4];
  __shared__ float invden[4];
  const int tid = threadIdx.x;
  const int rbase = blockIdx.x << 5;
  if (tid < 128) {
    const int u = tid >> 2, h = tid & 3;
    float l = es[((rbase + u) << 2) + h] + ed[(rbase << 2) + h];
    exs[u][h] = (l < 0.0f) ? 0.2f * l : l;
  }
  __syncthreads();
  if (tid < 4) {
    const int h = tid;
    float m = -1e30f;
    for (int u = 0; u < 32; ++u) m = fmaxf(m, exs[u][h]);
    float s = 0.0f;
    for (int u = 0; u < 32; ++u) { float e = expf(exs[u][h] - m); exs[u][h] = e; s += e; }
    s += exs[0][h];                        // duplicate 0->0 edge
    invden[h] = 1.0f / (s + 1e-9f);
  }
  __syncthreads();
  const int h = tid >> 6;
  const float h0 = hfeat[(rbase << 8) + tid];
  float s = exs[0][h] * h0;
  for (int u = 0; u < 32; ++u)
    s += exs[u][h] * hfeat[((rbase + u) << 8) + tid];
  const float bias = gb[tid];
  const float inv1 = 1.0f / (1.0f + 1e-9f);
  yout[(rbase << 8) + tid] = gelu_t(s * invden[h] + bias);
  const float gv = gelu_t(h0 * inv1 + bias);
  for (int v = 1; v < 32; ++v)
    yout[((rbase + v) << 8) + tid] = gv;
}

// ---- launch -----------------------------------------------------------------
extern "C" void kernel_launch(void* const* d_in, const int* in_sizes, int n_in,
                              void* d_out, int out_size, void* d_ws, size_t ws_size,
                              hipStream_t stream) {
  (void)in_sizes; (void)n_in; (void)out_size; (void)ws_size;
  const float* states = (const float*)d_in[0];
  const float* Wx1 = (const float*)d_in[1];
  const float* Wh1 = (const float*)d_in[2];
  const float* b1  = (const float*)d_in[3];
  const float* Wx2 = (const float*)d_in[4];
  const float* Wh2 = (const float*)d_in[5];
  const float* b2  = (const float*)d_in[6];
  const float* gW1 = (const float*)d_in[7];
  const float* gas1 = (const float*)d_in[8];
  const float* gad1 = (const float*)d_in[9];
  const float* gb1 = (const float*)d_in[10];
  const float* gW2 = (const float*)d_in[11];
  const float* gas2 = (const float*)d_in[12];
  const float* gad2 = (const float*)d_in[13];
  const float* gb2 = (const float*)d_in[14];

  float* ws = (float*)d_ws;
  float* pair0 = ws;                       // 2*NB floats (h1|h2 plane)
  float* pair1 = ws + 2 * (size_t)NB;      // 2*NB floats
  float* xg    = ws + 4 * (size_t)NB;      // NB floats
  float* xT    = ws + 5 * (size_t)NB;      // 800*2048 floats
  float* Wp1   = xT + 800 * 2048;          // 256*272*4 = 278528
  float* Wp2   = Wp1 + 278528;             // 256*512*4 = 524288
  unsigned* bar = (unsigned*)(Wp2 + 524288);
  // GAT aliases (pair buffers dead after lstm)
  float* y1    = pair0;
  float* hfeat = pair0 + NB;
  float* es    = pair1;
  float* ed    = pair1 + 2048 * 4;
  float* dout  = (float*)d_out;

  pack_w<<<dim3(2048), dim3(256), 0, stream>>>(Wx1, Wh1, Wx2, Wh2, Wp1, Wp2, bar);
  transpose_x<<<dim3(32 * 13), dim3(256), 0, stream>>>(states, xT);

  void* args[] = { (void*)&xT, (void*)&Wp1, (void*)&Wp2, (void*)&b1, (void*)&b2,
                   (void*)&pair0, (void*)&pair1, (void*)&xg, (void*)&bar };
  hipError_t err = hipLaunchCooperativeKernel((void*)lstm_fused, dim3(256), dim3(1024),
                                              args, 0, stream);
  if (err != hipSuccess) {
    // Fallback: grid == 1 block/CU capacity, co-resident anyway. NEVER drop
    // the launch silently (R8: zero-output failure).
    lstm_fused<<<dim3(256), dim3(1024), 0, stream>>>(xT, Wp1, Wp2, b1, b2,
                                                     pair0, pair1, xg, bar);
  }

  gat_feat<<<dim3(256), dim3(256), 0, stream>>>(xg, gW1, gas1, gad1, hfeat, es, ed);
  gat_out<<<dim3(64), dim3(256), 0, stream>>>(hfeat, es, ed, gb1, y1);
  gat_feat<<<dim3(256), dim3(256), 0, stream>>>(y1, gW2, gas2, gad2, hfeat, es, ed);
  gat_out<<<dim3(64), dim3(256), 0, stream>>>(hfeat, es, ed, gb2, dout);
}

// Round 14
// 2177.253 us; speedup vs baseline: 2.6309x; 1.7924x over previous
//
#include <hip/hip_runtime.h>

#define TSTEPS 50
#define NB (2048 * 256)

typedef __attribute__((ext_vector_type(8))) short short8;
typedef __attribute__((ext_vector_type(4))) float f32x4;

__device__ __forceinline__ float sigm(float x) { return 1.0f / (1.0f + expf(-x)); }
__device__ __forceinline__ float gelu_t(float x) {
  float x3 = x * x * x;
  return 0.5f * x * (1.0f + tanhf(0.7978845608028654f * (x + 0.044715f * x3)));
}

__device__ __forceinline__ f32x4 mfma_bf16(short8 a, short8 b, f32x4 c) {
  return __builtin_amdgcn_mfma_f32_16x16x32_bf16(a, b, c, 0, 0, 0);
}

// fp32 -> bf16 (RNE) hi/lo split: hi+lo reconstructs x to ~2^-18 relative.
__device__ __forceinline__ ushort f2bf(float x) {
  unsigned u = __builtin_bit_cast(unsigned, x);
  return (ushort)((u + 0x7FFFu + ((u >> 16) & 1u)) >> 16);
}
__device__ __forceinline__ float bf2f(ushort b) {
  unsigned u = (unsigned)b << 16;
  return __builtin_bit_cast(float, u);
}
__device__ __forceinline__ void bsplit(float x, ushort& hi, ushort& lo) {
  hi = f2bf(x);
  lo = f2bf(x - bf2f(hi));
}

// m-group barrier (32 blocks, one XCD: blk&7==mg). Plain __threadfence pair
// (R4-proven; R6's buffer_inv = 4.4GB disaster). No runtime-indexed local
// arrays anywhere (R9: 34GB scratch).
__device__ __forceinline__ void mg_barrier(unsigned* bar, unsigned target) {
  __syncthreads();
  if (threadIdx.x == 0) {
    __threadfence();
    atomicAdd(bar, 1u);
    while (atomicAdd(bar, 0u) < target) __builtin_amdgcn_s_sleep(4);
    __threadfence();
  }
  __syncthreads();
}

// Prep: split x into bf16 hi/lo planes; build pre-fragmented hi/lo W streams.
// Wm layout (bf16 units): [jg][nt][ks][pl][lane 0..63][i 0..7] -- a wave's
// B-fragment load = one coalesced 1KB global_load_dwordx4 per (nt,ks,pl).
// Fragment mapping (16x16x32): B[k][col]: col = lane&15, k = ks*32+(lane>>4)*8+i.
// col-within-block: (nt*2 + ((lane>>3)&1))*256 + jg*8 + (lane&7)  [gate-major].
__global__ void __launch_bounds__(256)
prep(const float* __restrict__ states,
     const float* __restrict__ Wx1, const float* __restrict__ Wh1,
     const float* __restrict__ Wx2, const float* __restrict__ Wh2,
     ushort* __restrict__ xh, ushort* __restrict__ xl,
     ushort* __restrict__ wm1, ushort* __restrict__ wm2,
     unsigned* __restrict__ bar)
{
  const size_t idx = (size_t)blockIdx.x * 256 + threadIdx.x;
  if (blockIdx.x == 0 && threadIdx.x < 256) bar[threadIdx.x] = 0u;
  if (idx < 1638400) {                       // x split: 2048*800
    ushort h, l; bsplit(states[idx], h, l);
    xh[idx] = h; xl[idx] = l;
  }
  if (idx < 589824) {                        // Wm1: 32jg*2nt*9ks*2pl*512
    int e = (int)idx;
    int i = e & 7, lane = (e >> 3) & 63, pl = (e >> 9) & 1;
    int s = (e >> 10) % 18, jg = e / 18432;
    int ks = s % 9, nt = s / 9;
    int col = (nt * 2 + ((lane >> 3) & 1)) * 256 + jg * 8 + (lane & 7);
    int kg = ks * 32 + ((lane >> 4) & 3) * 8 + i;
    float w = 0.0f;
    if (ks == 0) { if (kg < 16) w = Wx1[kg * 1024 + col]; }  // x K padded to 32
    else w = Wh1[(kg - 32) * 1024 + col];
    ushort h, l; bsplit(w, h, l);
    wm1[e] = pl ? l : h;
  }
  if (idx < 1048576) {                       // Wm2: 32jg*2nt*16ks*2pl*512
    int e = (int)idx;
    int i = e & 7, lane = (e >> 3) & 63, pl = (e >> 9) & 1;
    int s = (e >> 10) & 31, jg = e >> 15;
    int ks = s & 15, nt = s >> 4;
    int col = (nt * 2 + ((lane >> 3) & 1)) * 256 + jg * 8 + (lane & 7);
    int kg = ks * 32 + ((lane >> 4) & 3) * 8 + i;
    float w = (kg < 256) ? Wx2[kg * 1024 + col] : Wh2[(kg - 256) * 1024 + col];
    ushort h, l; bsplit(w, h, l);
    wm2[e] = pl ? l : h;
  }
}

// Persistent fused 2-layer LSTM + pool, split-bf16 MFMA edition.
// grid 256 = 8 mg (256 seqs, XCD=blk&7) x 32 jg (8 jcols = 32 gate-cols);
// block 1024 = 16 waves: waves 0-7 layer1 (M-tiles 0-7 + 8-15 via mtl),
// waves 8-15 layer2. Per wave: 2 M-tiles x 2 N-tiles, acc[2][2] f32x4.
// A (h hi/lo bf16) staged in XOR-swizzled LDS chunks [256 rows][64 k];
// dual-use: h1 chunks feed L1 (Wh1) AND L2 (Wx2). x chunk K=16 (zeros in
// A-frag lanes k>=16). Epilogue: shfl_xor(8) pairs gates (i,g)|(f,o).
__global__ void __launch_bounds__(1024, 1)
lstm_fused(const ushort* __restrict__ xh, const ushort* __restrict__ xl,
           const ushort* __restrict__ wm1, const ushort* __restrict__ wm2,
           const float* __restrict__ b1, const float* __restrict__ b2,
           ushort* __restrict__ hp, float* __restrict__ xg,
           unsigned* __restrict__ bar)
{
  __shared__ __align__(16) ushort As0[32768];   // 64KB: [hi 256x64 | lo]
  __shared__ __align__(16) ushort As1[32768];   // 64KB
  __shared__ __align__(16) ushort Asx[8192];    // 16KB: x [hi 256x16 | lo]

  const int tid = threadIdx.x;
  const int lane = tid & 63;
  const int w = __builtin_amdgcn_readfirstlane(tid >> 6);  // 0..15
  const int lw = w >> 3, mt2 = w & 7;
  const int blk = blockIdx.x;
  const int mg = blk & 7, jg = blk >> 3;
  const int mgbase = mg << 8;                  // 256 seqs
  const int gA = (lane >> 3) & 1;
  const int jcolg = (jg << 3) + (lane & 7);
  unsigned* mybar = bar + (mg << 4);

  const char* wmb = lw ? (const char*)(wm2 + (size_t)jg * 32768)
                       : (const char*)(wm1 + (size_t)jg * 18432);
  const int KSL = lw ? 16 : 9;

  const float* bl = lw ? b2 : b1;
  const float bn0 = bl[gA * 256 + jcolg];
  const float bn1 = bl[(2 + gA) * 256 + jcolg];
  const f32x4 bv0 = {bn0, bn0, bn0, bn0};
  const f32x4 bv1 = {bn1, bn1, bn1, bn1};

  float cst[2][4] = {{0,0,0,0},{0,0,0,0}};
  float pool[2][4] = {{0,0,0,0},{0,0,0,0}};
  f32x4 acc[2][2];                             // [mtl][nt], all idx unrolled

  const int srow = tid >> 2, sq = tid & 3;     // staging: 256 rows x 4 pieces

  for (int p = 0; p <= TSTEPS; ++p) {
    const bool doL1 = (p < TSTEPS), doL2 = (p >= 1), doH2 = (p >= 2);
    const int nch = doL2 ? (doH2 ? 8 : 4) : 0;
    const ushort* rdh = hp + (size_t)(((p + 1) & 1) * 2) * 1048576;
    const ushort* rdl = rdh + 1048576;
    ushort* wrh = hp + (size_t)((p & 1) * 2) * 1048576;
    ushort* wrl = wrh + 1048576;
    const bool meL1 = (lw == 0) && doL1;
    const bool meL2 = (lw == 1) && doL2;

    if (meL1 || meL2) { acc[0][0] = bv0; acc[0][1] = bv1; acc[1][0] = bv0; acc[1][1] = bv1; }

    auto consume_x = [&]() {
      short8 Bx[2][2];
      #pragma unroll
      for (int nt = 0; nt < 2; ++nt)
        #pragma unroll
        for (int pl = 0; pl < 2; ++pl)
          Bx[nt][pl] = *(const short8*)(wmb + (size_t)(((nt * 9) * 2 + pl) << 10) + lane * 16);
      #pragma unroll
      for (int mtl = 0; mtl < 2; ++mtl) {
        const int rowb = (mt2 + 8 * mtl) * 16 + (lane & 15);
        short8 Ah = {0,0,0,0,0,0,0,0}, Al = {0,0,0,0,0,0,0,0};
        if ((lane >> 4) < 2) {                 // k<16 real; k>=16 zero-pad
          const int off = rowb * 32 + ((((lane >> 4) & 1) ^ (rowb & 1)) << 4);
          Ah = *(const short8*)((const char*)Asx + off);
          Al = *(const short8*)((const char*)Asx + off + 8192);
        }
        #pragma unroll
        for (int nt = 0; nt < 2; ++nt) {
          f32x4 t = acc[mtl][nt];
          t = mfma_bf16(Ah, Bx[nt][0], t);
          t = mfma_bf16(Ah, Bx[nt][1], t);
          t = mfma_bf16(Al, Bx[nt][0], t);
          acc[mtl][nt] = t;
        }
      }
    };
    auto consume_h = [&](const ushort* As, int ci) {
      const bool doMe = lw ? doL2 : (doL1 && ci < 4);
      if (!doMe) return;
      const int ks0 = lw ? (2 * ci) : (1 + 2 * ci);
      short8 B[2][2][2];
      #pragma unroll
      for (int nt = 0; nt < 2; ++nt)
        #pragma unroll
        for (int ks = 0; ks < 2; ++ks)
          #pragma unroll
          for (int pl = 0; pl < 2; ++pl)
            B[nt][ks][pl] = *(const short8*)(wmb +
                ((size_t)((nt * KSL + ks0 + ks) * 2 + pl) << 10) + lane * 16);
      #pragma unroll
      for (int mtl = 0; mtl < 2; ++mtl) {
        const int rowb = (mt2 + 8 * mtl) * 16 + (lane & 15);
        #pragma unroll
        for (int ks = 0; ks < 2; ++ks) {
          const int k16 = ks * 4 + (lane >> 4);
          const int off = rowb * 128 + ((k16 ^ (rowb & 7)) << 4);
          const short8 Ah = *(const short8*)((const char*)As + off);
          const short8 Al = *(const short8*)((const char*)As + off + 32768);
          #pragma unroll
          for (int nt = 0; nt < 2; ++nt) {
            f32x4 t = acc[mtl][nt];
            t = mfma_bf16(Ah, B[nt][ks][0], t);
            t = mfma_bf16(Ah, B[nt][ks][1], t);
            t = mfma_bf16(Al, B[nt][ks][0], t);
            acc[mtl][nt] = t;
          }
        }
      }
    };

    // ---- stage x chunk + h chunk 0, then T14 pipeline over h chunks ----
    uint4 Gx, Ga, Gb, Gc, Gd;
    if (doL1) {
      const ushort* xs = ((sq < 2) ? xh : xl) + (size_t)(mgbase + srow) * 800 + p * 16 + (sq & 1) * 8;
      Gx = *(const uint4*)xs;
    }
    if (nch) {
      const ushort* sh = rdh + (size_t)(mgbase + srow) * 512 + sq * 16;
      const ushort* sl = rdl + (size_t)(mgbase + srow) * 512 + sq * 16;
      Ga = *(const uint4*)sh; Gb = *(const uint4*)(sh + 8);
      Gc = *(const uint4*)sl; Gd = *(const uint4*)(sl + 8);
    }
    if (doL1) {
      const int xoff = srow * 32 + (((sq & 1) ^ (srow & 1)) << 4) + ((sq >> 1) << 13);
      *(uint4*)((char*)Asx + xoff) = Gx;
    }
    const int o0 = srow * 128 + (((sq * 2) ^ (srow & 7)) << 4);
    const int o1 = srow * 128 + (((sq * 2 + 1) ^ (srow & 7)) << 4);
    if (nch) {
      *(uint4*)((char*)As0 + o0) = Ga;
      *(uint4*)((char*)As0 + o1) = Gb;
      *(uint4*)((char*)As0 + 32768 + o0) = Gc;
      *(uint4*)((char*)As0 + 32768 + o1) = Gd;
    }
    __syncthreads();

    if (nch == 0) {
      if (meL1) consume_x();
    } else {
      int cur = 0;
      for (int ci = 0; ci < nch; ++ci) {
        if (ci + 1 < nch) {
          const ushort* sh = rdh + (size_t)(mgbase + srow) * 512 + (ci + 1) * 64 + sq * 16;
          const ushort* sl = rdl + (size_t)(mgbase + srow) * 512 + (ci + 1) * 64 + sq * 16;
          Ga = *(const uint4*)sh; Gb = *(const uint4*)(sh + 8);
          Gc = *(const uint4*)sl; Gd = *(const uint4*)(sl + 8);
        }
        if (ci == 0 && meL1) consume_x();
        consume_h(cur ? As1 : As0, ci);
        if (ci + 1 < nch) {
          ushort* nb = cur ? As0 : As1;
          *(uint4*)((char*)nb + o0) = Ga;
          *(uint4*)((char*)nb + o1) = Gb;
          *(uint4*)((char*)nb + 32768 + o0) = Gc;
          *(uint4*)((char*)nb + 32768 + o1) = Gd;
          cur ^= 1;
        }
        __syncthreads();
      }
    }

    // ---- epilogue: lane(gA=0) owns (i,g); partner lane^8 owns (f,o) ----
    if (meL1 || meL2) {
      #pragma unroll
      for (int mtl = 0; mtl < 2; ++mtl) {
        #pragma unroll
        for (int r = 0; r < 4; ++r) {
          const float zA = acc[mtl][0][r];
          const float zB = acc[mtl][1][r];
          const float pA = __shfl_xor(zA, 8);
          const float pB = __shfl_xor(zB, 8);
          const float iv = sigm(zA), fv = sigm(pA);
          const float gv = tanhf(zB), ov = sigm(pB);
          const float cc = fv * cst[mtl][r] + iv * gv;
          cst[mtl][r] = cc;
          const float h = ov * tanhf(cc);
          if (gA == 0) {
            const int seq = mgbase + (mt2 + 8 * mtl) * 16 + (lane >> 4) * 4 + r;
            ushort hu, lu; bsplit(h, hu, lu);
            const size_t base = (size_t)seq * 512 + lw * 256 + jcolg;
            wrh[base] = hu; wrl[base] = lu;
            if (lw) pool[mtl][r] += h;
          }
        }
      }
    }

    if (p < TSTEPS) mg_barrier(mybar, (unsigned)(p + 1) * 32u);
  }

  if (lw == 1 && gA == 0) {
    #pragma unroll
    for (int mtl = 0; mtl < 2; ++mtl)
      #pragma unroll
      for (int r = 0; r < 4; ++r) {
        const int seq = mgbase + (mt2 + 8 * mtl) * 16 + (lane >> 4) * 4 + r;
        xg[(size_t)seq * 256 + jcolg] = pool[mtl][r] * (1.0f / 50.0f);
      }
  }
}

// ---- GAT (verified R1-R13, fp32) --------------------------------------------
__global__ void __launch_bounds__(256)
gat_feat(const float* __restrict__ xin, const float* __restrict__ gW,
         const float* __restrict__ a_src, const float* __restrict__ a_dst,
         float* __restrict__ hfeat, float* __restrict__ es, float* __restrict__ ed)
{
  __shared__ float Xs[8][260];
  const int tid = threadIdx.x;
  const int r0 = blockIdx.x << 3;
  #pragma unroll
  for (int i = 0; i < 8; ++i) Xs[i][tid] = xin[((r0 + i) << 8) + tid];
  __syncthreads();
  float acc[8];
  #pragma unroll
  for (int i = 0; i < 8; ++i) acc[i] = 0.0f;
  for (int k = 0; k < 256; k += 4) {
    const float w0 = gW[(k + 0) * 256 + tid];
    const float w1 = gW[(k + 1) * 256 + tid];
    const float w2 = gW[(k + 2) * 256 + tid];
    const float w3 = gW[(k + 3) * 256 + tid];
    #pragma unroll
    for (int i = 0; i < 8; ++i)
      acc[i] += Xs[i][k] * w0 + Xs[i][k + 1] * w1 + Xs[i][k + 2] * w2 + Xs[i][k + 3] * w3;
  }
  const int h = tid >> 6;
  const int lane = tid & 63;
  const float asv = a_src[(h << 6) + lane];
  const float adv = a_dst[(h << 6) + lane];
  #pragma unroll
  for (int i = 0; i < 8; ++i) {
    hfeat[((r0 + i) << 8) + tid] = acc[i];
    float pse = acc[i] * asv;
    float pde = acc[i] * adv;
    #pragma unroll
    for (int off = 32; off > 0; off >>= 1) {
      pse += __shfl_down(pse, off);
      pde += __shfl_down(pde, off);
    }
    if (lane == 0) {
      es[((r0 + i) << 2) + h] = pse;
      ed[((r0 + i) << 2) + h] = pde;
    }
  }
}

__global__ void __launch_bounds__(256)
gat_out(const float* __restrict__ hfeat, const float* __restrict__ es, const float* __restrict__ ed,
        const float* __restrict__ gb, float* __restrict__ yout)
{
  __shared__ float exs[32][4];
  __shared__ float invden[4];
  const int tid = threadIdx.x;
  const int rbase = blockIdx.x << 5;
  if (tid < 128) {
    const int u = tid >> 2, h = tid & 3;
    float l = es[((rbase + u) << 2) + h] + ed[(rbase << 2) + h];
    exs[u][h] = (l < 0.0f) ? 0.2f * l : l;
  }
  __syncthreads();
  if (tid < 4) {
    const int h = tid;
    float m = -1e30f;
    for (int u = 0; u < 32; ++u) m = fmaxf(m, exs[u][h]);
    float s = 0.0f;
    for (int u = 0; u < 32; ++u) { float e = expf(exs[u][h] - m); exs[u][h] = e; s += e; }
    s += exs[0][h];
    invden[h] = 1.0f / (s + 1e-9f);
  }
  __syncthreads();
  const int h = tid >> 6;
  const float h0 = hfeat[(rbase << 8) + tid];
  float s = exs[0][h] * h0;
  for (int u = 0; u < 32; ++u)
    s += exs[u][h] * hfeat[((rbase + u) << 8) + tid];
  const float bias = gb[tid];
  const float inv1 = 1.0f / (1.0f + 1e-9f);
  yout[(rbase << 8) + tid] = gelu_t(s * invden[h] + bias);
  const float gv = gelu_t(h0 * inv1 + bias);
  for (int v = 1; v < 32; ++v)
    yout[((rbase + v) << 8) + tid] = gv;
}

// ---- launch -----------------------------------------------------------------
extern "C" void kernel_launch(void* const* d_in, const int* in_sizes, int n_in,
                              void* d_out, int out_size, void* d_ws, size_t ws_size,
                              hipStream_t stream) {
  (void)in_sizes; (void)n_in; (void)out_size; (void)ws_size;
  const float* states = (const float*)d_in[0];
  const float* Wx1 = (const float*)d_in[1];
  const float* Wh1 = (const float*)d_in[2];
  const float* b1  = (const float*)d_in[3];
  const float* Wx2 = (const float*)d_in[4];
  const float* Wh2 = (const float*)d_in[5];
  const float* b2  = (const float*)d_in[6];
  const float* gW1 = (const float*)d_in[7];
  const float* gas1 = (const float*)d_in[8];
  const float* gad1 = (const float*)d_in[9];
  const float* gb1 = (const float*)d_in[10];
  const float* gW2 = (const float*)d_in[11];
  const float* gas2 = (const float*)d_in[12];
  const float* gad2 = (const float*)d_in[13];
  const float* gb2 = (const float*)d_in[14];

  char* wsb = (char*)d_ws;
  ushort* hp  = (ushort*)wsb;                          // 4 planes x 2MB = 8MB
  ushort* xh  = (ushort*)(wsb + 8388608);              // 3.125MB
  ushort* xl  = xh + 1638400;                          // 3.125MB
  ushort* wm1 = (ushort*)(wsb + 8388608 + 6553600);    // 1.125MB
  ushort* wm2 = wm1 + 589824;                          // 2MB
  float*  xg  = (float*)(wsb + 8388608 + 6553600 + 1179648 + 2097152);  // 2MB
  unsigned* bar = (unsigned*)((char*)xg + 2097152);
  // GAT aliases (hp planes dead after lstm)
  float* y1    = (float*)wsb;
  float* hfeat = y1 + NB;
  float* es    = hfeat + NB;
  float* ed    = es + 2048 * 4;
  float* dout  = (float*)d_out;

  prep<<<dim3(6400), dim3(256), 0, stream>>>(states, Wx1, Wh1, Wx2, Wh2,
                                             xh, xl, wm1, wm2, bar);

  void* args[] = { (void*)&xh, (void*)&xl, (void*)&wm1, (void*)&wm2,
                   (void*)&b1, (void*)&b2, (void*)&hp, (void*)&xg, (void*)&bar };
  hipError_t err = hipLaunchCooperativeKernel((void*)lstm_fused, dim3(256), dim3(1024),
                                              args, 0, stream);
  if (err != hipSuccess) {
    // grid == 1 block/CU capacity -> co-resident under plain launch too.
    // NEVER drop the launch silently (R8).
    lstm_fused<<<dim3(256), dim3(1024), 0, stream>>>(xh, xl, wm1, wm2,
                                                     b1, b2, hp, xg, bar);
  }

  gat_feat<<<dim3(256), dim3(256), 0, stream>>>(xg, gW1, gas1, gad1, hfeat, es, ed);
  gat_out<<<dim3(64), dim3(256), 0, stream>>>(hfeat, es, ed, gb1, y1);
  gat_feat<<<dim3(256), dim3(256), 0, stream>>>(y1, gW2, gas2, gad2, hfeat, es, ed);
  gat_out<<<dim3(64), dim3(256), 0, stream>>>(hfeat, es, ed, gb2, dout);
}

// Round 15
// 1933.399 us; speedup vs baseline: 2.9627x; 1.1261x over previous
//
#include <hip/hip_runtime.h>

#define TSTEPS 50
#define NB (2048 * 256)

typedef __attribute__((ext_vector_type(8))) short short8;
typedef __attribute__((ext_vector_type(4))) float f32x4;

__device__ __forceinline__ float sigm(float x) { return 1.0f / (1.0f + expf(-x)); }
__device__ __forceinline__ float gelu_t(float x) {
  float x3 = x * x * x;
  return 0.5f * x * (1.0f + tanhf(0.7978845608028654f * (x + 0.044715f * x3)));
}

__device__ __forceinline__ f32x4 mfma_bf16(short8 a, short8 b, f32x4 c) {
  return __builtin_amdgcn_mfma_f32_16x16x32_bf16(a, b, c, 0, 0, 0);
}

// fp32 -> bf16 (RNE) hi/lo split: hi+lo reconstructs x to ~2^-18 relative.
__device__ __forceinline__ ushort f2bf(float x) {
  unsigned u = __builtin_bit_cast(unsigned, x);
  return (ushort)((u + 0x7FFFu + ((u >> 16) & 1u)) >> 16);
}
__device__ __forceinline__ float bf2f(ushort b) {
  unsigned u = (unsigned)b << 16;
  return __builtin_bit_cast(float, u);
}
__device__ __forceinline__ void bsplit(float x, ushort& hi, ushort& lo) {
  hi = f2bf(x);
  lo = f2bf(x - bf2f(hi));
}

// m-group barrier (32 blocks, one XCD: blk&7==mg). Plain __threadfence pair
// (R4-proven; R6's buffer_inv = 4.4GB disaster). No runtime-indexed local
// arrays anywhere (R9: 34GB scratch).
__device__ __forceinline__ void mg_barrier(unsigned* bar, unsigned target) {
  __syncthreads();
  if (threadIdx.x == 0) {
    __threadfence();
    atomicAdd(bar, 1u);
    while (atomicAdd(bar, 0u) < target) __builtin_amdgcn_s_sleep(4);
    __threadfence();
  }
  __syncthreads();
}

// Prep (verified R14, unchanged): x hi/lo split + pre-fragmented hi/lo W.
// Wm layout (bf16): [jg][nt][ks][pl][lane][i]; fragment mapping 16x16x32:
// col = lane&15 -> (nt*2+((lane>>3)&1))*256 + jg*8 + (lane&7); k = ks*32+(lane>>4)*8+i.
__global__ void __launch_bounds__(256)
prep(const float* __restrict__ states,
     const float* __restrict__ Wx1, const float* __restrict__ Wh1,
     const float* __restrict__ Wx2, const float* __restrict__ Wh2,
     ushort* __restrict__ xh, ushort* __restrict__ xl,
     ushort* __restrict__ wm1, ushort* __restrict__ wm2,
     unsigned* __restrict__ bar)
{
  const size_t idx = (size_t)blockIdx.x * 256 + threadIdx.x;
  if (blockIdx.x == 0 && threadIdx.x < 256) bar[threadIdx.x] = 0u;
  if (idx < 1638400) {
    ushort h, l; bsplit(states[idx], h, l);
    xh[idx] = h; xl[idx] = l;
  }
  if (idx < 589824) {                        // Wm1: 32jg*2nt*9ks*2pl*512
    int e = (int)idx;
    int i = e & 7, lane = (e >> 3) & 63, pl = (e >> 9) & 1;
    int s = (e >> 10) % 18, jg = e / 18432;
    int ks = s % 9, nt = s / 9;
    int col = (nt * 2 + ((lane >> 3) & 1)) * 256 + jg * 8 + (lane & 7);
    int kg = ks * 32 + ((lane >> 4) & 3) * 8 + i;
    float w = 0.0f;
    if (ks == 0) { if (kg < 16) w = Wx1[kg * 1024 + col]; }
    else w = Wh1[(kg - 32) * 1024 + col];
    ushort h, l; bsplit(w, h, l);
    wm1[e] = pl ? l : h;
  }
  if (idx < 1048576) {                       // Wm2: 32jg*2nt*16ks*2pl*512
    int e = (int)idx;
    int i = e & 7, lane = (e >> 3) & 63, pl = (e >> 9) & 1;
    int s = (e >> 10) & 31, jg = e >> 15;
    int ks = s & 15, nt = s >> 4;
    int col = (nt * 2 + ((lane >> 3) & 1)) * 256 + jg * 8 + (lane & 7);
    int kg = ks * 32 + ((lane >> 4) & 3) * 8 + i;
    float w = (kg < 256) ? Wx2[kg * 1024 + col] : Wh2[(kg - 256) * 1024 + col];
    ushort h, l; bsplit(w, h, l);
    wm2[e] = pl ? l : h;
  }
}

// Persistent fused 2-layer LSTM + pool, split-bf16 MFMA, W-in-LDS edition.
// grid 256 = 8 mg x 32 jg; block 1024 = 16 waves (8 L1 + 8 L2), each wave
// 2 M-tiles x 2 N-tiles. W slices (pre-fragmented) live in LDS for the whole
// kernel: B-frags = conflict-free ds_read_b128. A-frags (h hi/lo bf16) read
// DIRECTLY from global (L2-resident: per-XCD phase working set ~1MB).
// No intra-phase syncthreads; one mg_barrier per phase.
__global__ void __launch_bounds__(1024, 1)
lstm_fused(const ushort* __restrict__ xh, const ushort* __restrict__ xl,
           const ushort* __restrict__ wm1, const ushort* __restrict__ wm2,
           const float* __restrict__ b1, const float* __restrict__ b2,
           ushort* __restrict__ hp, float* __restrict__ xg,
           unsigned* __restrict__ bar)
{
  __shared__ __align__(16) ushort W1s[18432];   // 36KB [nt2][ks9][pl2][512]
  __shared__ __align__(16) ushort W2s[32768];   // 64KB [nt2][ks16][pl2][512]

  const int tid = threadIdx.x;
  const int lane = tid & 63;
  const int w = __builtin_amdgcn_readfirstlane(tid >> 6);  // 0..15
  const int lw = w >> 3, mt2 = w & 7;
  const int blk = blockIdx.x;
  const int mg = blk & 7, jg = blk >> 3;
  const int mgbase = mg << 8;                  // 256 seqs
  const int gA = (lane >> 3) & 1;
  const int jcolg = (jg << 3) + (lane & 7);
  unsigned* mybar = bar + (mg << 4);

  // ---- W slices -> LDS, once ----
  {
    const uint4* s1 = (const uint4*)(wm1 + (size_t)jg * 18432);
    uint4* d1 = (uint4*)W1s;
    for (int i = tid; i < 2304; i += 1024) d1[i] = s1[i];
    const uint4* s2 = (const uint4*)(wm2 + (size_t)jg * 32768);
    uint4* d2 = (uint4*)W2s;
    for (int i = tid; i < 4096; i += 1024) d2[i] = s2[i];
  }
  __syncthreads();

  const float* bl = lw ? b2 : b1;
  const float bn0 = bl[gA * 256 + jcolg];
  const float bn1 = bl[(2 + gA) * 256 + jcolg];
  const f32x4 bv0 = {bn0, bn0, bn0, bn0};
  const f32x4 bv1 = {bn1, bn1, bn1, bn1};

  float cst[2][4] = {{0,0,0,0},{0,0,0,0}};
  float pool[2][4] = {{0,0,0,0},{0,0,0,0}};
  f32x4 acc[2][2];

  const int rowb0 = mt2 * 16 + (lane & 15);
  const int rowb1 = rowb0 + 128;
  const int kq = lane >> 4;                    // 0..3
  const char* w1c = (const char*)W1s;
  const char* w2c = (const char*)W2s;
  const size_t arow0 = (size_t)(mgbase + rowb0) * 512;
  const size_t arow1 = (size_t)(mgbase + rowb1) * 512;

  auto tri = [&](f32x4 c, short8 ah, short8 al, short8 bh, short8 blo) {
    c = mfma_bf16(ah, bh, c);
    c = mfma_bf16(ah, blo, c);
    c = mfma_bf16(al, bh, c);
    return c;
  };

  for (int p = 0; p <= TSTEPS; ++p) {
    const bool doL1 = (p < TSTEPS), doL2 = (p >= 1), doH2 = (p >= 2);
    const ushort* rdh = hp + (size_t)(((p + 1) & 1) * 2) * 1048576;
    const ushort* rdl = rdh + 1048576;
    ushort* wrh = hp + (size_t)((p & 1) * 2) * 1048576;
    ushort* wrl = wrh + 1048576;
    const bool meL1 = (lw == 0) && doL1;
    const bool meL2 = (lw == 1) && doL2;

    if (meL1 || meL2) { acc[0][0] = bv0; acc[0][1] = bv1; acc[1][0] = bv0; acc[1][1] = bv1; }

    if (meL1) {
      // ---- ks slot 0: x (K=16 real, k>=16 zero-padded; W rows there = 0) ----
      short8 Ah0 = {0,0,0,0,0,0,0,0}, Al0 = {0,0,0,0,0,0,0,0};
      short8 Ah1 = {0,0,0,0,0,0,0,0}, Al1 = {0,0,0,0,0,0,0,0};
      if (kq < 2) {
        const size_t xo0 = (size_t)(mgbase + rowb0) * 800 + p * 16 + kq * 8;
        const size_t xo1 = (size_t)(mgbase + rowb1) * 800 + p * 16 + kq * 8;
        Ah0 = *(const short8*)(xh + xo0);
        Al0 = *(const short8*)(xl + xo0);
        Ah1 = *(const short8*)(xh + xo1);
        Al1 = *(const short8*)(xl + xo1);
      }
      {
        const short8 B00 = *(const short8*)(w1c + (0 * 2 + 0) * 1024 + lane * 16);
        const short8 B01 = *(const short8*)(w1c + (0 * 2 + 1) * 1024 + lane * 16);
        const short8 B10 = *(const short8*)(w1c + (18 + 0) * 1024 + lane * 16);
        const short8 B11 = *(const short8*)(w1c + (18 + 1) * 1024 + lane * 16);
        acc[0][0] = tri(acc[0][0], Ah0, Al0, B00, B01);
        acc[0][1] = tri(acc[0][1], Ah0, Al0, B10, B11);
        acc[1][0] = tri(acc[1][0], Ah1, Al1, B00, B01);
        acc[1][1] = tri(acc[1][1], Ah1, Al1, B10, B11);
      }
      // ---- ks slots 1..8: h1[p-1] ----
      if (p >= 1) {
        #pragma unroll 4
        for (int ks = 1; ks <= 8; ++ks) {
          const size_t ko = (size_t)((ks - 1) * 32 + kq * 8);
          const short8 Ah0h = *(const short8*)(rdh + arow0 + ko);
          const short8 Al0h = *(const short8*)(rdl + arow0 + ko);
          const short8 Ah1h = *(const short8*)(rdh + arow1 + ko);
          const short8 Al1h = *(const short8*)(rdl + arow1 + ko);
          const short8 B00 = *(const short8*)(w1c + ((0 * 9 + ks) * 2 + 0) * 1024 + lane * 16);
          const short8 B01 = *(const short8*)(w1c + ((0 * 9 + ks) * 2 + 1) * 1024 + lane * 16);
          const short8 B10 = *(const short8*)(w1c + ((1 * 9 + ks) * 2 + 0) * 1024 + lane * 16);
          const short8 B11 = *(const short8*)(w1c + ((1 * 9 + ks) * 2 + 1) * 1024 + lane * 16);
          acc[0][0] = tri(acc[0][0], Ah0h, Al0h, B00, B01);
          acc[0][1] = tri(acc[0][1], Ah0h, Al0h, B10, B11);
          acc[1][0] = tri(acc[1][0], Ah1h, Al1h, B00, B01);
          acc[1][1] = tri(acc[1][1], Ah1h, Al1h, B10, B11);
        }
      }
    }
    if (meL2) {
      // ---- ks 0..7: h1[p-1] (W2x); ks 8..15: h2[p-2] (W2h) ----
      const int ksend = doH2 ? 16 : 8;
      #pragma unroll 4
      for (int ks = 0; ks < ksend; ++ks) {
        const size_t ko = (size_t)(ks * 32 + kq * 8);
        const short8 Ah0h = *(const short8*)(rdh + arow0 + ko);
        const short8 Al0h = *(const short8*)(rdl + arow0 + ko);
        const short8 Ah1h = *(const short8*)(rdh + arow1 + ko);
        const short8 Al1h = *(const short8*)(rdl + arow1 + ko);
        const short8 B00 = *(const short8*)(w2c + ((0 * 16 + ks) * 2 + 0) * 1024 + lane * 16);
        const short8 B01 = *(const short8*)(w2c + ((0 * 16 + ks) * 2 + 1) * 1024 + lane * 16);
        const short8 B10 = *(const short8*)(w2c + ((1 * 16 + ks) * 2 + 0) * 1024 + lane * 16);
        const short8 B11 = *(const short8*)(w2c + ((1 * 16 + ks) * 2 + 1) * 1024 + lane * 16);
        acc[0][0] = tri(acc[0][0], Ah0h, Al0h, B00, B01);
        acc[0][1] = tri(acc[0][1], Ah0h, Al0h, B10, B11);
        acc[1][0] = tri(acc[1][0], Ah1h, Al1h, B00, B01);
        acc[1][1] = tri(acc[1][1], Ah1h, Al1h, B10, B11);
      }
    }

    // ---- epilogue (verified R14): lane gA=0 owns (i,g); lane^8 owns (f,o) ----
    if (meL1 || meL2) {
      #pragma unroll
      for (int mtl = 0; mtl < 2; ++mtl) {
        #pragma unroll
        for (int r = 0; r < 4; ++r) {
          const float zA = acc[mtl][0][r];
          const float zB = acc[mtl][1][r];
          const float pA = __shfl_xor(zA, 8);
          const float pB = __shfl_xor(zB, 8);
          const float iv = sigm(zA), fv = sigm(pA);
          const float gv = tanhf(zB), ov = sigm(pB);
          const float cc = fv * cst[mtl][r] + iv * gv;
          cst[mtl][r] = cc;
          const float h = ov * tanhf(cc);
          if (gA == 0) {
            const int seq = mgbase + (mt2 + 8 * mtl) * 16 + (lane >> 4) * 4 + r;
            ushort hu, lu; bsplit(h, hu, lu);
            const size_t base = (size_t)seq * 512 + lw * 256 + jcolg;
            wrh[base] = hu; wrl[base] = lu;
            if (lw) pool[mtl][r] += h;
          }
        }
      }
    }

    if (p < TSTEPS) mg_barrier(mybar, (unsigned)(p + 1) * 32u);
  }

  if (lw == 1 && gA == 0) {
    #pragma unroll
    for (int mtl = 0; mtl < 2; ++mtl)
      #pragma unroll
      for (int r = 0; r < 4; ++r) {
        const int seq = mgbase + (mt2 + 8 * mtl) * 16 + (lane >> 4) * 4 + r;
        xg[(size_t)seq * 256 + jcolg] = pool[mtl][r] * (1.0f / 50.0f);
      }
  }
}

// ---- GAT (verified R1-R14, fp32) --------------------------------------------
__global__ void __launch_bounds__(256)
gat_feat(const float* __restrict__ xin, const float* __restrict__ gW,
         const float* __restrict__ a_src, const float* __restrict__ a_dst,
         float* __restrict__ hfeat, float* __restrict__ es, float* __restrict__ ed)
{
  __shared__ float Xs[8][260];
  const int tid = threadIdx.x;
  const int r0 = blockIdx.x << 3;
  #pragma unroll
  for (int i = 0; i < 8; ++i) Xs[i][tid] = xin[((r0 + i) << 8) + tid];
  __syncthreads();
  float acc[8];
  #pragma unroll
  for (int i = 0; i < 8; ++i) acc[i] = 0.0f;
  for (int k = 0; k < 256; k += 4) {
    const float w0 = gW[(k + 0) * 256 + tid];
    const float w1 = gW[(k + 1) * 256 + tid];
    const float w2 = gW[(k + 2) * 256 + tid];
    const float w3 = gW[(k + 3) * 256 + tid];
    #pragma unroll
    for (int i = 0; i < 8; ++i)
      acc[i] += Xs[i][k] * w0 + Xs[i][k + 1] * w1 + Xs[i][k + 2] * w2 + Xs[i][k + 3] * w3;
  }
  const int h = tid >> 6;
  const int lane = tid & 63;
  const float asv = a_src[(h << 6) + lane];
  const float adv = a_dst[(h << 6) + lane];
  #pragma unroll
  for (int i = 0; i < 8; ++i) {
    hfeat[((r0 + i) << 8) + tid] = acc[i];
    float pse = acc[i] * asv;
    float pde = acc[i] * adv;
    #pragma unroll
    for (int off = 32; off > 0; off >>= 1) {
      pse += __shfl_down(pse, off);
      pde += __shfl_down(pde, off);
    }
    if (lane == 0) {
      es[((r0 + i) << 2) + h] = pse;
      ed[((r0 + i) << 2) + h] = pde;
    }
  }
}

__global__ void __launch_bounds__(256)
gat_out(const float* __restrict__ hfeat, const float* __restrict__ es, const float* __restrict__ ed,
        const float* __restrict__ gb, float* __restrict__ yout)
{
  __shared__ float exs[32][4];
  __shared__ float invden[4];
  const int tid = threadIdx.x;
  const int rbase = blockIdx.x << 5;
  if (tid < 128) {
    const int u = tid >> 2, h = tid & 3;
    float l = es[((rbase + u) << 2) + h] + ed[(rbase << 2) + h];
    exs[u][h] = (l < 0.0f) ? 0.2f * l : l;
  }
  __syncthreads();
  if (tid < 4) {
    const int h = tid;
    float m = -1e30f;
    for (int u = 0; u < 32; ++u) m = fmaxf(m, exs[u][h]);
    float s = 0.0f;
    for (int u = 0; u < 32; ++u) { float e = expf(exs[u][h] - m); exs[u][h] = e; s += e; }
    s += exs[0][h];
    invden[h] = 1.0f / (s + 1e-9f);
  }
  __syncthreads();
  const int h = tid >> 6;
  const float h0 = hfeat[(rbase << 8) + tid];
  float s = exs[0][h] * h0;
  for (int u = 0; u < 32; ++u)
    s += exs[u][h] * hfeat[((rbase + u) << 8) + tid];
  const float bias = gb[tid];
  const float inv1 = 1.0f / (1.0f + 1e-9f);
  yout[(rbase << 8) + tid] = gelu_t(s * invden[h] + bias);
  const float gv = gelu_t(h0 * inv1 + bias);
  for (int v = 1; v < 32; ++v)
    yout[((rbase + v) << 8) + tid] = gv;
}

// ---- launch -----------------------------------------------------------------
extern "C" void kernel_launch(void* const* d_in, const int* in_sizes, int n_in,
                              void* d_out, int out_size, void* d_ws, size_t ws_size,
                              hipStream_t stream) {
  (void)in_sizes; (void)n_in; (void)out_size; (void)ws_size;
  const float* states = (const float*)d_in[0];
  const float* Wx1 = (const float*)d_in[1];
  const float* Wh1 = (const float*)d_in[2];
  const float* b1  = (const float*)d_in[3];
  const float* Wx2 = (const float*)d_in[4];
  const float* Wh2 = (const float*)d_in[5];
  const float* b2  = (const float*)d_in[6];
  const float* gW1 = (const float*)d_in[7];
  const float* gas1 = (const float*)d_in[8];
  const float* gad1 = (const float*)d_in[9];
  const float* gb1 = (const float*)d_in[10];
  const float* gW2 = (const float*)d_in[11];
  const float* gas2 = (const float*)d_in[12];
  const float* gad2 = (const float*)d_in[13];
  const float* gb2 = (const float*)d_in[14];

  char* wsb = (char*)d_ws;
  ushort* hp  = (ushort*)wsb;                          // 4 planes x 2MB = 8MB
  ushort* xh  = (ushort*)(wsb + 8388608);
  ushort* xl  = xh + 1638400;
  ushort* wm1 = (ushort*)(wsb + 8388608 + 6553600);
  ushort* wm2 = wm1 + 589824;
  float*  xg  = (float*)(wsb + 8388608 + 6553600 + 1179648 + 2097152);
  unsigned* bar = (unsigned*)((char*)xg + 2097152);
  // GAT aliases (hp planes dead after lstm)
  float* y1    = (float*)wsb;
  float* hfeat = y1 + NB;
  float* es    = hfeat + NB;
  float* ed    = es + 2048 * 4;
  float* dout  = (float*)d_out;

  prep<<<dim3(6400), dim3(256), 0, stream>>>(states, Wx1, Wh1, Wx2, Wh2,
                                             xh, xl, wm1, wm2, bar);

  void* args[] = { (void*)&xh, (void*)&xl, (void*)&wm1, (void*)&wm2,
                   (void*)&b1, (void*)&b2, (void*)&hp, (void*)&xg, (void*)&bar };
  hipError_t err = hipLaunchCooperativeKernel((void*)lstm_fused, dim3(256), dim3(1024),
                                              args, 0, stream);
  if (err != hipSuccess) {
    // grid == 1 block/CU capacity -> co-resident under plain launch too.
    // NEVER drop the launch silently (R8).
    lstm_fused<<<dim3(256), dim3(1024), 0, stream>>>(xh, xl, wm1, wm2,
                                                     b1, b2, hp, xg, bar);
  }

  gat_feat<<<dim3(256), dim3(256), 0, stream>>>(xg, gW1, gas1, gad1, hfeat, es, ed);
  gat_out<<<dim3(64), dim3(256), 0, stream>>>(hfeat, es, ed, gb1, y1);
  gat_feat<<<dim3(256), dim3(256), 0, stream>>>(y1, gW2, gas2, gad2, hfeat, es, ed);
  gat_out<<<dim3(64), dim3(256), 0, stream>>>(hfeat, es, ed, gb2, dout);
}

// Round 16
// 1668.675 us; speedup vs baseline: 3.4327x; 1.1586x over previous
//
#include <hip/hip_runtime.h>

#define TSTEPS 50
#define NB (2048 * 256)

typedef __attribute__((ext_vector_type(8))) short short8;
typedef __attribute__((ext_vector_type(4))) float f32x4;

__device__ __forceinline__ float sigm(float x) { return 1.0f / (1.0f + expf(-x)); }
__device__ __forceinline__ float gelu_t(float x) {
  float x3 = x * x * x;
  return 0.5f * x * (1.0f + tanhf(0.7978845608028654f * (x + 0.044715f * x3)));
}

__device__ __forceinline__ f32x4 mfma_bf16(short8 a, short8 b, f32x4 c) {
  return __builtin_amdgcn_mfma_f32_16x16x32_bf16(a, b, c, 0, 0, 0);
}

// fp32 -> bf16 (RNE) hi/lo split: hi+lo reconstructs x to ~2^-18 relative.
__device__ __forceinline__ ushort f2bf(float x) {
  unsigned u = __builtin_bit_cast(unsigned, x);
  return (ushort)((u + 0x7FFFu + ((u >> 16) & 1u)) >> 16);
}
__device__ __forceinline__ float bf2f(ushort b) {
  unsigned u = (unsigned)b << 16;
  return __builtin_bit_cast(float, u);
}
__device__ __forceinline__ void bsplit(float x, ushort& hi, ushort& lo) {
  hi = f2bf(x);
  lo = f2bf(x - bf2f(hi));
}

// m-group barrier (32 blocks, one XCD: blk&7==mg). Plain __threadfence pair
// (R4-proven; R6's buffer_inv = 4.4GB disaster). No runtime-indexed local
// arrays anywhere (R9: 34GB scratch).
__device__ __forceinline__ void mg_barrier(unsigned* bar, unsigned target) {
  __syncthreads();
  if (threadIdx.x == 0) {
    __threadfence();
    atomicAdd(bar, 1u);
    while (atomicAdd(bar, 0u) < target) __builtin_amdgcn_s_sleep(4);
    __threadfence();
  }
  __syncthreads();
}

// Prep (verified R14/R15, unchanged): x hi/lo split + pre-fragmented hi/lo W.
__global__ void __launch_bounds__(256)
prep(const float* __restrict__ states,
     const float* __restrict__ Wx1, const float* __restrict__ Wh1,
     const float* __restrict__ Wx2, const float* __restrict__ Wh2,
     ushort* __restrict__ xh, ushort* __restrict__ xl,
     ushort* __restrict__ wm1, ushort* __restrict__ wm2,
     unsigned* __restrict__ bar)
{
  const size_t idx = (size_t)blockIdx.x * 256 + threadIdx.x;
  if (blockIdx.x == 0 && threadIdx.x < 256) bar[threadIdx.x] = 0u;
  if (idx < 1638400) {
    ushort h, l; bsplit(states[idx], h, l);
    xh[idx] = h; xl[idx] = l;
  }
  if (idx < 589824) {                        // Wm1: 32jg*2nt*9ks*2pl*512
    int e = (int)idx;
    int i = e & 7, lane = (e >> 3) & 63, pl = (e >> 9) & 1;
    int s = (e >> 10) % 18, jg = e / 18432;
    int ks = s % 9, nt = s / 9;
    int col = (nt * 2 + ((lane >> 3) & 1)) * 256 + jg * 8 + (lane & 7);
    int kg = ks * 32 + ((lane >> 4) & 3) * 8 + i;
    float w = 0.0f;
    if (ks == 0) { if (kg < 16) w = Wx1[kg * 1024 + col]; }
    else w = Wh1[(kg - 32) * 1024 + col];
    ushort h, l; bsplit(w, h, l);
    wm1[e] = pl ? l : h;
  }
  if (idx < 1048576) {                       // Wm2: 32jg*2nt*16ks*2pl*512
    int e = (int)idx;
    int i = e & 7, lane = (e >> 3) & 63, pl = (e >> 9) & 1;
    int s = (e >> 10) & 31, jg = e >> 15;
    int ks = s & 15, nt = s >> 4;
    int col = (nt * 2 + ((lane >> 3) & 1)) * 256 + jg * 8 + (lane & 7);
    int kg = ks * 32 + ((lane >> 4) & 3) * 8 + i;
    float w = (kg < 256) ? Wx2[kg * 1024 + col] : Wh2[(kg - 256) * 1024 + col];
    ushort h, l; bsplit(w, h, l);
    wm2[e] = pl ? l : h;
  }
}

// Persistent fused 2-layer LSTM + pool, split-bf16 MFMA, W-in-LDS, UNIFIED
// waves: each of 16 waves owns ONE 16-seq M-tile and computes BOTH layers.
// Each h1 A-fragment load feeds 12 MFMAs (Wh1->z1 AND Wx2->z2): per-wave A
// traffic 800->544 B/lane/phase, per-block 768->512KB, balanced work.
// ks loops fully unrolled so all 32 A-loads/phase are scheduler-visible.
__global__ void __launch_bounds__(1024, 1)
lstm_fused(const ushort* __restrict__ xh, const ushort* __restrict__ xl,
           const ushort* __restrict__ wm1, const ushort* __restrict__ wm2,
           const float* __restrict__ b1, const float* __restrict__ b2,
           ushort* __restrict__ hp, float* __restrict__ xg,
           unsigned* __restrict__ bar)
{
  __shared__ __align__(16) ushort W1s[18432];   // 36KB [nt2][ks9][pl2][512]
  __shared__ __align__(16) ushort W2s[32768];   // 64KB [nt2][ks16][pl2][512]

  const int tid = threadIdx.x;
  const int lane = tid & 63;
  const int mt = __builtin_amdgcn_readfirstlane(tid >> 6);  // 0..15: M-tile
  const int blk = blockIdx.x;
  const int mg = blk & 7, jg = blk >> 3;
  const int mgbase = mg << 8;                  // 256 seqs
  const int gA = (lane >> 3) & 1;
  const int jcolg = (jg << 3) + (lane & 7);
  unsigned* mybar = bar + (mg << 4);

  // ---- W slices -> LDS, once ----
  {
    const uint4* s1 = (const uint4*)(wm1 + (size_t)jg * 18432);
    uint4* d1 = (uint4*)W1s;
    for (int i = tid; i < 2304; i += 1024) d1[i] = s1[i];
    const uint4* s2 = (const uint4*)(wm2 + (size_t)jg * 32768);
    uint4* d2 = (uint4*)W2s;
    for (int i = tid; i < 4096; i += 1024) d2[i] = s2[i];
  }
  __syncthreads();

  const float b1n0 = b1[gA * 256 + jcolg];
  const float b1n1 = b1[(2 + gA) * 256 + jcolg];
  const float b2n0 = b2[gA * 256 + jcolg];
  const float b2n1 = b2[(2 + gA) * 256 + jcolg];
  const f32x4 bv10 = {b1n0, b1n0, b1n0, b1n0};
  const f32x4 bv11 = {b1n1, b1n1, b1n1, b1n1};
  const f32x4 bv20 = {b2n0, b2n0, b2n0, b2n0};
  const f32x4 bv21 = {b2n1, b2n1, b2n1, b2n1};

  float c1s[4] = {0,0,0,0}, c2s[4] = {0,0,0,0}, pool[4] = {0,0,0,0};
  f32x4 a1[2], a2[2];                          // [nt] accumulators per layer

  const int rowb = mt * 16 + (lane & 15);
  const int kq = lane >> 4;                    // 0..3
  const char* w1c = (const char*)W1s;
  const char* w2c = (const char*)W2s;
  const size_t arow = (size_t)(mgbase + rowb) * 512;

  auto tri = [&](f32x4 c, short8 ah, short8 al, short8 bh, short8 blo) {
    c = mfma_bf16(ah, bh, c);
    c = mfma_bf16(ah, blo, c);
    c = mfma_bf16(al, bh, c);
    return c;
  };

  for (int p = 0; p <= TSTEPS; ++p) {
    const bool doL1 = (p < TSTEPS), doL2 = (p >= 1), doH2 = (p >= 2);
    const ushort* rdh = hp + (size_t)(((p + 1) & 1) * 2) * 1048576;
    const ushort* rdl = rdh + 1048576;
    ushort* wrh = hp + (size_t)((p & 1) * 2) * 1048576;
    ushort* wrl = wrh + 1048576;

    if (doL1) { a1[0] = bv10; a1[1] = bv11; }
    if (doL2) { a2[0] = bv20; a2[1] = bv21; }

    if (doL1) {
      // ---- x slot (K=16 real, k>=16 zero-padded; W rows there = 0) ----
      short8 Ah = {0,0,0,0,0,0,0,0}, Al = {0,0,0,0,0,0,0,0};
      if (kq < 2) {
        const size_t xo = (size_t)(mgbase + rowb) * 800 + p * 16 + kq * 8;
        Ah = *(const short8*)(xh + xo);
        Al = *(const short8*)(xl + xo);
      }
      const short8 B00 = *(const short8*)(w1c + 0 * 1024 + lane * 16);
      const short8 B01 = *(const short8*)(w1c + 1 * 1024 + lane * 16);
      const short8 B10 = *(const short8*)(w1c + 18 * 1024 + lane * 16);
      const short8 B11 = *(const short8*)(w1c + 19 * 1024 + lane * 16);
      a1[0] = tri(a1[0], Ah, Al, B00, B01);
      a1[1] = tri(a1[1], Ah, Al, B10, B11);
    }
    if (doL2) {
      // ---- h1[p-1]: feeds BOTH L1 (Wh1, slot ks+1) and L2 (Wx2, slot ks) ----
      #pragma unroll
      for (int ks = 0; ks < 8; ++ks) {
        const size_t ko = (size_t)(ks * 32 + kq * 8);
        const short8 Ah = *(const short8*)(rdh + arow + ko);
        const short8 Al = *(const short8*)(rdl + arow + ko);
        if (doL1) {
          const short8 B00 = *(const short8*)(w1c + ((0 * 9 + ks + 1) * 2 + 0) * 1024 + lane * 16);
          const short8 B01 = *(const short8*)(w1c + ((0 * 9 + ks + 1) * 2 + 1) * 1024 + lane * 16);
          const short8 B10 = *(const short8*)(w1c + ((1 * 9 + ks + 1) * 2 + 0) * 1024 + lane * 16);
          const short8 B11 = *(const short8*)(w1c + ((1 * 9 + ks + 1) * 2 + 1) * 1024 + lane * 16);
          a1[0] = tri(a1[0], Ah, Al, B00, B01);
          a1[1] = tri(a1[1], Ah, Al, B10, B11);
        }
        const short8 C00 = *(const short8*)(w2c + ((0 * 16 + ks) * 2 + 0) * 1024 + lane * 16);
        const short8 C01 = *(const short8*)(w2c + ((0 * 16 + ks) * 2 + 1) * 1024 + lane * 16);
        const short8 C10 = *(const short8*)(w2c + ((1 * 16 + ks) * 2 + 0) * 1024 + lane * 16);
        const short8 C11 = *(const short8*)(w2c + ((1 * 16 + ks) * 2 + 1) * 1024 + lane * 16);
        a2[0] = tri(a2[0], Ah, Al, C00, C01);
        a2[1] = tri(a2[1], Ah, Al, C10, C11);
      }
      // ---- h2[p-2]: L2 only (W2h, slots 8..15) ----
      if (doH2) {
        #pragma unroll
        for (int ks = 8; ks < 16; ++ks) {
          const size_t ko = (size_t)(ks * 32 + kq * 8);
          const short8 Ah = *(const short8*)(rdh + arow + ko);
          const short8 Al = *(const short8*)(rdl + arow + ko);
          const short8 C00 = *(const short8*)(w2c + ((0 * 16 + ks) * 2 + 0) * 1024 + lane * 16);
          const short8 C01 = *(const short8*)(w2c + ((0 * 16 + ks) * 2 + 1) * 1024 + lane * 16);
          const short8 C10 = *(const short8*)(w2c + ((1 * 16 + ks) * 2 + 0) * 1024 + lane * 16);
          const short8 C11 = *(const short8*)(w2c + ((1 * 16 + ks) * 2 + 1) * 1024 + lane * 16);
          a2[0] = tri(a2[0], Ah, Al, C00, C01);
          a2[1] = tri(a2[1], Ah, Al, C10, C11);
        }
      }
    }

    // ---- epilogues (verified math): gA=0 owns (i,g); lane^8 owns (f,o) ----
    if (doL1) {
      #pragma unroll
      for (int r = 0; r < 4; ++r) {
        const float zA = a1[0][r], zB = a1[1][r];
        const float pA = __shfl_xor(zA, 8), pB = __shfl_xor(zB, 8);
        const float iv = sigm(zA), fv = sigm(pA);
        const float gv = tanhf(zB), ov = sigm(pB);
        const float cc = fv * c1s[r] + iv * gv;
        c1s[r] = cc;
        const float h = ov * tanhf(cc);
        if (gA == 0) {
          const int seq = mgbase + mt * 16 + (lane >> 4) * 4 + r;
          ushort hu, lu; bsplit(h, hu, lu);
          const size_t base = (size_t)seq * 512 + jcolg;
          wrh[base] = hu; wrl[base] = lu;
        }
      }
    }
    if (doL2) {
      #pragma unroll
      for (int r = 0; r < 4; ++r) {
        const float zA = a2[0][r], zB = a2[1][r];
        const float pA = __shfl_xor(zA, 8), pB = __shfl_xor(zB, 8);
        const float iv = sigm(zA), fv = sigm(pA);
        const float gv = tanhf(zB), ov = sigm(pB);
        const float cc = fv * c2s[r] + iv * gv;
        c2s[r] = cc;
        const float h = ov * tanhf(cc);
        pool[r] += h;
        if (gA == 0) {
          const int seq = mgbase + mt * 16 + (lane >> 4) * 4 + r;
          ushort hu, lu; bsplit(h, hu, lu);
          const size_t base = (size_t)seq * 512 + 256 + jcolg;
          wrh[base] = hu; wrl[base] = lu;
        }
      }
    }

    if (p < TSTEPS) mg_barrier(mybar, (unsigned)(p + 1) * 32u);
  }

  if (gA == 0) {
    #pragma unroll
    for (int r = 0; r < 4; ++r) {
      const int seq = mgbase + mt * 16 + (lane >> 4) * 4 + r;
      xg[(size_t)seq * 256 + jcolg] = pool[r] * (1.0f / 50.0f);
    }
  }
}

// ---- GAT (verified R1-R15, fp32) --------------------------------------------
__global__ void __launch_bounds__(256)
gat_feat(const float* __restrict__ xin, const float* __restrict__ gW,
         const float* __restrict__ a_src, const float* __restrict__ a_dst,
         float* __restrict__ hfeat, float* __restrict__ es, float* __restrict__ ed)
{
  __shared__ float Xs[8][260];
  const int tid = threadIdx.x;
  const int r0 = blockIdx.x << 3;
  #pragma unroll
  for (int i = 0; i < 8; ++i) Xs[i][tid] = xin[((r0 + i) << 8) + tid];
  __syncthreads();
  float acc[8];
  #pragma unroll
  for (int i = 0; i < 8; ++i) acc[i] = 0.0f;
  for (int k = 0; k < 256; k += 4) {
    const float w0 = gW[(k + 0) * 256 + tid];
    const float w1 = gW[(k + 1) * 256 + tid];
    const float w2 = gW[(k + 2) * 256 + tid];
    const float w3 = gW[(k + 3) * 256 + tid];
    #pragma unroll
    for (int i = 0; i < 8; ++i)
      acc[i] += Xs[i][k] * w0 + Xs[i][k + 1] * w1 + Xs[i][k + 2] * w2 + Xs[i][k + 3] * w3;
  }
  const int h = tid >> 6;
  const int lane = tid & 63;
  const float asv = a_src[(h << 6) + lane];
  const float adv = a_dst[(h << 6) + lane];
  #pragma unroll
  for (int i = 0; i < 8; ++i) {
    hfeat[((r0 + i) << 8) + tid] = acc[i];
    float pse = acc[i] * asv;
    float pde = acc[i] * adv;
    #pragma unroll
    for (int off = 32; off > 0; off >>= 1) {
      pse += __shfl_down(pse, off);
      pde += __shfl_down(pde, off);
    }
    if (lane == 0) {
      es[((r0 + i) << 2) + h] = pse;
      ed[((r0 + i) << 2) + h] = pde;
    }
  }
}

__global__ void __launch_bounds__(256)
gat_out(const float* __restrict__ hfeat, const float* __restrict__ es, const float* __restrict__ ed,
        const float* __restrict__ gb, float* __restrict__ yout)
{
  __shared__ float exs[32][4];
  __shared__ float invden[4];
  const int tid = threadIdx.x;
  const int rbase = blockIdx.x << 5;
  if (tid < 128) {
    const int u = tid >> 2, h = tid & 3;
    float l = es[((rbase + u) << 2) + h] + ed[(rbase << 2) + h];
    exs[u][h] = (l < 0.0f) ? 0.2f * l : l;
  }
  __syncthreads();
  if (tid < 4) {
    const int h = tid;
    float m = -1e30f;
    for (int u = 0; u < 32; ++u) m = fmaxf(m, exs[u][h]);
    float s = 0.0f;
    for (int u = 0; u < 32; ++u) { float e = expf(exs[u][h] - m); exs[u][h] = e; s += e; }
    s += exs[0][h];
    invden[h] = 1.0f / (s + 1e-9f);
  }
  __syncthreads();
  const int h = tid >> 6;
  const float h0 = hfeat[(rbase << 8) + tid];
  float s = exs[0][h] * h0;
  for (int u = 0; u < 32; ++u)
    s += exs[u][h] * hfeat[((rbase + u) << 8) + tid];
  const float bias = gb[tid];
  const float inv1 = 1.0f / (1.0f + 1e-9f);
  yout[(rbase << 8) + tid] = gelu_t(s * invden[h] + bias);
  const float gv = gelu_t(h0 * inv1 + bias);
  for (int v = 1; v < 32; ++v)
    yout[((rbase + v) << 8) + tid] = gv;
}

// ---- launch -----------------------------------------------------------------
extern "C" void kernel_launch(void* const* d_in, const int* in_sizes, int n_in,
                              void* d_out, int out_size, void* d_ws, size_t ws_size,
                              hipStream_t stream) {
  (void)in_sizes; (void)n_in; (void)out_size; (void)ws_size;
  const float* states = (const float*)d_in[0];
  const float* Wx1 = (const float*)d_in[1];
  const float* Wh1 = (const float*)d_in[2];
  const float* b1  = (const float*)d_in[3];
  const float* Wx2 = (const float*)d_in[4];
  const float* Wh2 = (const float*)d_in[5];
  const float* b2  = (const float*)d_in[6];
  const float* gW1 = (const float*)d_in[7];
  const float* gas1 = (const float*)d_in[8];
  const float* gad1 = (const float*)d_in[9];
  const float* gb1 = (const float*)d_in[10];
  const float* gW2 = (const float*)d_in[11];
  const float* gas2 = (const float*)d_in[12];
  const float* gad2 = (const float*)d_in[13];
  const float* gb2 = (const float*)d_in[14];

  char* wsb = (char*)d_ws;
  ushort* hp  = (ushort*)wsb;                          // 4 planes x 2MB = 8MB
  ushort* xh  = (ushort*)(wsb + 8388608);
  ushort* xl  = xh + 1638400;
  ushort* wm1 = (ushort*)(wsb + 8388608 + 6553600);
  ushort* wm2 = wm1 + 589824;
  float*  xg  = (float*)(wsb + 8388608 + 6553600 + 1179648 + 2097152);
  unsigned* bar = (unsigned*)((char*)xg + 2097152);
  // GAT aliases (hp planes dead after lstm)
  float* y1    = (float*)wsb;
  float* hfeat = y1 + NB;
  float* es    = hfeat + NB;
  float* ed    = es + 2048 * 4;
  float* dout  = (float*)d_out;

  prep<<<dim3(6400), dim3(256), 0, stream>>>(states, Wx1, Wh1, Wx2, Wh2,
                                             xh, xl, wm1, wm2, bar);

  void* args[] = { (void*)&xh, (void*)&xl, (void*)&wm1, (void*)&wm2,
                   (void*)&b1, (void*)&b2, (void*)&hp, (void*)&xg, (void*)&bar };
  hipError_t err = hipLaunchCooperativeKernel((void*)lstm_fused, dim3(256), dim3(1024),
                                              args, 0, stream);
  if (err != hipSuccess) {
    // grid == 1 block/CU capacity -> co-resident under plain launch too.
    // NEVER drop the launch silently (R8).
    lstm_fused<<<dim3(256), dim3(1024), 0, stream>>>(xh, xl, wm1, wm2,
                                                     b1, b2, hp, xg, bar);
  }

  gat_feat<<<dim3(256), dim3(256), 0, stream>>>(xg, gW1, gas1, gad1, hfeat, es, ed);
  gat_out<<<dim3(64), dim3(256), 0, stream>>>(hfeat, es, ed, gb1, y1);
  gat_feat<<<dim3(256), dim3(256), 0, stream>>>(y1, gW2, gas2, gad2, hfeat, es, ed);
  gat_out<<<dim3(64), dim3(256), 0, stream>>>(hfeat, es, ed, gb2, dout);
}